// Round 5
// baseline (546.424 us; speedup 1.0000x reference)
//
#include <hip/hip_runtime.h>
#include <hip/hip_bf16.h>
#include <stdint.h>

#define DEV __device__ __forceinline__

typedef __bf16 bf16x8 __attribute__((ext_vector_type(8)));
typedef float f32x4 __attribute__((ext_vector_type(4)));
typedef unsigned short ushort8_t __attribute__((ext_vector_type(8)));
typedef unsigned short ushort4_t __attribute__((ext_vector_type(4)));

constexpr int S = 2048;
constexpr int D = 4096;
constexpr int H = 32;
constexpr int HD = 128;
constexpr float kSc = 0.08838834764831845f * 1.4426950408889634f;  // 1/sqrt(HD) * log2(e)

DEV unsigned short f2bf(float f) {
    uint32_t u = __builtin_bit_cast(uint32_t, f);
    u += 0x7fffu + ((u >> 16) & 1u);
    return (unsigned short)(u >> 16);
}
DEV float bf2f(unsigned short h) {
    uint32_t u = ((uint32_t)h) << 16;
    return __builtin_bit_cast(float, u);
}

DEV void gload_lds16(const void* g, void* l) {
    __builtin_amdgcn_global_load_lds(
        (const __attribute__((address_space(1))) void*)g,
        (__attribute__((address_space(3))) void*)l,
        16, 0, 0);
}

DEV f32x4 mfma16(bf16x8 a, bf16x8 b, f32x4 c) {
    return __builtin_amdgcn_mfma_f32_16x16x32_bf16(a, b, c, 0, 0, 0);
}

// ---------------- fp32 -> bf16 convert, all 5 tensors in one dispatch -------
__global__ __launch_bounds__(256) void cvt_all(const float* __restrict__ hs,
                                               const float* __restrict__ w0,
                                               const float* __restrict__ w1,
                                               const float* __restrict__ w2,
                                               const float* __restrict__ w3,
                                               unsigned short* __restrict__ hsb,
                                               unsigned short* __restrict__ o0,
                                               unsigned short* __restrict__ o1,
                                               unsigned short* __restrict__ o2,
                                               unsigned short* __restrict__ o3) {
    const int b = blockIdx.x;
    const float* in;
    unsigned short* out;
    size_t blk;
    if (b < 4096) {
        in = hs; out = hsb; blk = (size_t)b;
    } else {
        const int i = b - 4096;
        const int w = i >> 13;
        const int r = i & 8191;
        in  = (w == 0) ? w0 : (w == 1) ? w1 : (w == 2) ? w2 : w3;
        out = (w == 0) ? o0 : (w == 1) ? o1 : (w == 2) ? o2 : o3;
        blk = (size_t)r;
    }
    const size_t i8 = blk * 256 + threadIdx.x;  // index in units of 8 elems
    f32x4 a = ((const f32x4*)in)[2 * i8];
    f32x4 c = ((const f32x4*)in)[2 * i8 + 1];
    ushort8_t o;
    o[0] = f2bf(a[0]); o[1] = f2bf(a[1]); o[2] = f2bf(a[2]); o[3] = f2bf(a[3]);
    o[4] = f2bf(c[0]); o[5] = f2bf(c[1]); o[6] = f2bf(c[2]); o[7] = f2bf(c[3]);
    ((ushort8_t*)out)[i8] = o;
}

// ---------------- fused QKV GEMM -------------------------------------------
// C[m][n] = sum_k hs[m][k] * W[n][k] for W in {Wq,Wk,Wv} selected per block.
// Grid 1536 = 96 n-tiles x 16 m-tiles. Each XCD (bid&7) owns a contiguous
// chunk of 12 n-tiles; within the chunk m varies FASTEST so the resident
// blocks of one XCD share a handful of B panels (L2) while A cycles via L3.
__global__ __launch_bounds__(256) void gemm_qkv(const unsigned short* __restrict__ A,
                                                const unsigned short* __restrict__ wq,
                                                const unsigned short* __restrict__ wk,
                                                const unsigned short* __restrict__ wv,
                                                unsigned short* __restrict__ Qb,
                                                unsigned short* __restrict__ Kb,
                                                unsigned short* __restrict__ Vt) {
    __shared__ unsigned short As[128 * 64];
    __shared__ unsigned short Bs[128 * 64];
    const int t = threadIdx.x;
    const int lane = t & 63;
    const int wid = t >> 6;
    const int g = lane >> 4;
    const int rl = lane & 15;

    const int bid = blockIdx.x;       // 1536 = 8 xcd * (12 n * 16 m)
    const int xcd = bid & 7;
    const int idx = bid >> 3;         // 0..191
    const int nl = idx >> 4;          // 0..11  (n-local, slow)
    const int mm = idx & 15;          // 0..15  (m, fast)
    const int xx = xcd * 12 + nl;     // 0..95
    const int m0 = mm * 128;
    const int n0g = xx * 128;
    const int wsel = n0g >> 12;       // 0:Q 1:K 2:V
    const int n0 = n0g & 4095;
    const unsigned short* B = (wsel == 0) ? wq : (wsel == 1) ? wk : wv;

    const int wm = (wid >> 1) * 64;
    const int wn = (wid & 1) * 64;
    constexpr int K = D, M = S, N = D;

    f32x4 acc[4][4] = {};

    for (int kt = 0; kt < K; kt += 64) {
#pragma unroll
        for (int r = 0; r < 4; ++r) {
            const int c = r * 256 + t;
            const int row = c >> 3;
            const int src = (c & 7) ^ (row & 7);
            const int dstChunk = r * 256 + wid * 64;
            gload_lds16(A + (size_t)(m0 + row) * K + kt + src * 8, &As[dstChunk * 8]);
            gload_lds16(B + (size_t)(n0 + row) * K + kt + src * 8, &Bs[dstChunk * 8]);
        }
        __syncthreads();
#pragma unroll
        for (int ks = 0; ks < 2; ++ks) {
            bf16x8 af[4], bfv[4];
#pragma unroll
            for (int i = 0; i < 4; ++i) {
                const int rowa = wm + i * 16 + rl;
                af[i] = *(const bf16x8*)&As[rowa * 64 + (((ks * 4 + g) ^ (rowa & 7)) << 3)];
                const int rowb = wn + i * 16 + rl;
                bfv[i] = *(const bf16x8*)&Bs[rowb * 64 + (((ks * 4 + g) ^ (rowb & 7)) << 3)];
            }
#pragma unroll
            for (int mi = 0; mi < 4; ++mi)
#pragma unroll
                for (int ni = 0; ni < 4; ++ni)
                    acc[mi][ni] = mfma16(af[mi], bfv[ni], acc[mi][ni]);
        }
        __syncthreads();
    }

#pragma unroll
    for (int mi = 0; mi < 4; ++mi) {
#pragma unroll
        for (int ni = 0; ni < 4; ++ni) {
            const int grow = m0 + wm + mi * 16 + g * 4;  // +r
            const int gcol = n0 + wn + ni * 16 + rl;
            if (wsel == 2) {  // V: transposed store  Vt[n][m]
                ushort4_t v;
#pragma unroll
                for (int r = 0; r < 4; ++r) v[r] = f2bf(acc[mi][ni][r]);
                *(ushort4_t*)&Vt[(size_t)gcol * M + grow] = v;
            } else {
                unsigned short* o = (wsel == 0) ? Qb : Kb;
#pragma unroll
                for (int r = 0; r < 4; ++r)
                    o[(size_t)(grow + r) * N + gcol] = f2bf(acc[mi][ni][r]);
            }
        }
    }
}

// ---------------- O-projection GEMM: fp32 C = A * Wo^T ----------------------
__global__ __launch_bounds__(256) void gemm_out(const unsigned short* __restrict__ A,
                                                const unsigned short* __restrict__ B,
                                                float* __restrict__ C) {
    __shared__ unsigned short As[128 * 64];
    __shared__ unsigned short Bs[128 * 64];
    const int t = threadIdx.x;
    const int lane = t & 63;
    const int wid = t >> 6;
    const int g = lane >> 4;
    const int rl = lane & 15;

    const int bid = blockIdx.x;       // 512 = 8 xcd * (4 n * 16 m)
    const int xcd = bid & 7;
    const int idx = bid >> 3;         // 0..63
    const int nl = idx >> 4;          // 0..3  (n-local, slow)
    const int mm = idx & 15;          // 0..15 (m, fast)
    const int m0 = mm * 128;
    const int n0 = (xcd * 4 + nl) * 128;

    const int wm = (wid >> 1) * 64;
    const int wn = (wid & 1) * 64;
    constexpr int K = D, N = D;

    f32x4 acc[4][4] = {};

    for (int kt = 0; kt < K; kt += 64) {
#pragma unroll
        for (int r = 0; r < 4; ++r) {
            const int c = r * 256 + t;
            const int row = c >> 3;
            const int src = (c & 7) ^ (row & 7);
            const int dstChunk = r * 256 + wid * 64;
            gload_lds16(A + (size_t)(m0 + row) * K + kt + src * 8, &As[dstChunk * 8]);
            gload_lds16(B + (size_t)(n0 + row) * K + kt + src * 8, &Bs[dstChunk * 8]);
        }
        __syncthreads();
#pragma unroll
        for (int ks = 0; ks < 2; ++ks) {
            bf16x8 af[4], bfv[4];
#pragma unroll
            for (int i = 0; i < 4; ++i) {
                const int rowa = wm + i * 16 + rl;
                af[i] = *(const bf16x8*)&As[rowa * 64 + (((ks * 4 + g) ^ (rowa & 7)) << 3)];
                const int rowb = wn + i * 16 + rl;
                bfv[i] = *(const bf16x8*)&Bs[rowb * 64 + (((ks * 4 + g) ^ (rowb & 7)) << 3)];
            }
#pragma unroll
            for (int mi = 0; mi < 4; ++mi)
#pragma unroll
                for (int ni = 0; ni < 4; ++ni)
                    acc[mi][ni] = mfma16(af[mi], bfv[ni], acc[mi][ni]);
        }
        __syncthreads();
    }

#pragma unroll
    for (int mi = 0; mi < 4; ++mi) {
#pragma unroll
        for (int ni = 0; ni < 4; ++ni) {
            const int grow = m0 + wm + mi * 16 + g * 4;
            const int gcol = n0 + wn + ni * 16 + rl;
#pragma unroll
            for (int r = 0; r < 4; ++r)
                C[(size_t)(grow + r) * N + gcol] = acc[mi][ni][r];
        }
    }
}

// ---------------- RoPE in place on Q and K ([S][D] bf16) --------------------
__global__ __launch_bounds__(256) void rope_kernel(unsigned short* __restrict__ Qb,
                                                   unsigned short* __restrict__ Kb,
                                                   const float* __restrict__ cosT,
                                                   const float* __restrict__ sinT) {
    const int i = blockIdx.x * 256 + threadIdx.x;  // S*H*8 threads
    const int j8 = i & 7;
    const int h = (i >> 3) & 31;
    const int s = i >> 8;
    const size_t base = (size_t)s * D + h * HD + j8 * 8;
    const float* cp = cosT + s * HD + j8 * 8;
    const float* sp = sinT + s * HD + j8 * 8;
    float c1[8], s1[8], c2[8], s2[8];
#pragma unroll
    for (int k = 0; k < 8; ++k) { c1[k] = cp[k]; s1[k] = sp[k]; c2[k] = cp[k + 64]; s2[k] = sp[k + 64]; }

#pragma unroll
    for (int w = 0; w < 2; ++w) {
        unsigned short* p = (w == 0 ? Qb : Kb) + base;
        const float f = (w == 0) ? kSc : 1.0f;
        ushort8_t x1 = *(ushort8_t*)p;
        ushort8_t x2 = *(ushort8_t*)(p + 64);
        ushort8_t o1, o2;
#pragma unroll
        for (int k = 0; k < 8; ++k) {
            const float a = bf2f(x1[k]);
            const float b = bf2f(x2[k]);
            o1[k] = f2bf((a * c1[k] - b * s1[k]) * f);
            o2[k] = f2bf((b * c2[k] + a * s2[k]) * f);
        }
        *(ushort8_t*)p = o1;
        *(ushort8_t*)(p + 64) = o2;
    }
}

// ---------------- causal flash attention (swapped-operand MFMA) -------------
constexpr int NQT = S / 128;  // 16 q-tiles
__global__ __launch_bounds__(256, 2) void flash_attn(const unsigned short* __restrict__ Q,
                                                     const unsigned short* __restrict__ K,
                                                     const unsigned short* __restrict__ V,
                                                     unsigned short* __restrict__ O) {
    __shared__ unsigned short Ks[2][64 * 128];  // [kv][hd], swizzled, dbuf
    __shared__ unsigned short Vs[128 * 64];     // [hd][kv], swizzled
    __shared__ unsigned short Ps[4][32 * 64];   // per-wave P, swizzled

    const int t = threadIdx.x;
    const int lane = t & 63;
    const int wid = t >> 6;
    const int g = lane >> 4;
    const int rl = lane & 15;
    const int bid = blockIdx.x;
    const int qt = (NQT - 1) - (bid >> 5);  // heavy tiles first
    const int h = bid & 31;                 // head in low bits: head-affine XCD
    const int q0 = qt * 128;
    const int wrow0 = q0 + wid * 32;

    bf16x8 qf[2][4];
#pragma unroll
    for (int mi = 0; mi < 2; ++mi) {
        const unsigned short* qp = Q + (size_t)(wrow0 + mi * 16 + rl) * D + h * HD;
#pragma unroll
        for (int ks = 0; ks < 4; ++ks) qf[mi][ks] = *(const bf16x8*)(qp + ks * 32 + g * 8);
    }

    f32x4 accO[2][8] = {};
    float m2s[2] = {-1e30f, -1e30f};
    float lsum[2] = {0.f, 0.f};

    // prologue: stage K tile 0 into buf 0
#pragma unroll
    for (int r = 0; r < 4; ++r) {
        const int c = r * 256 + t;
        const int rowk = c >> 4;
        const int srck = (c & 15) ^ (rowk & 7);
        gload_lds16(K + (size_t)rowk * D + h * HD + srck * 8,
                    &Ks[0][(r * 256 + wid * 64) * 8]);
    }
    __syncthreads();

    int cur = 0;
    const int ntiles = 2 * qt + 2;
    for (int kv = 0; kv < ntiles; ++kv) {
        const int kv0 = kv * 64;
        // stage V[kv] (single buffer) + prefetch K[kv+1] into other buffer
#pragma unroll
        for (int r = 0; r < 4; ++r) {
            const int c = r * 256 + t;
            const int rowv = c >> 3;
            const int srcv = (c & 7) ^ (rowv & 7);
            gload_lds16(V + (size_t)(h * HD + rowv) * S + kv0 + srcv * 8,
                        &Vs[(r * 256 + wid * 64) * 8]);
        }
        if (kv + 1 < ntiles) {
#pragma unroll
            for (int r = 0; r < 4; ++r) {
                const int c = r * 256 + t;
                const int rowk = c >> 4;
                const int srck = (c & 15) ^ (rowk & 7);
                gload_lds16(K + (size_t)(kv0 + 64 + rowk) * D + h * HD + srck * 8,
                            &Ks[cur ^ 1][(r * 256 + wid * 64) * 8]);
            }
        }

        const bool active = kv0 <= wrow0 + 31;  // wave-uniform
        if (active) {
            // sf[mi][nt][r] = S[q=wrow0+mi*16+rl][k=kv0+nt*16+g*4+r]
            f32x4 sf[2][4];
#pragma unroll
            for (int mi = 0; mi < 2; ++mi)
#pragma unroll
                for (int nt = 0; nt < 4; ++nt) sf[mi][nt] = f32x4{0.f, 0.f, 0.f, 0.f};
            __builtin_amdgcn_s_setprio(1);
#pragma unroll
            for (int nt = 0; nt < 4; ++nt) {
                const int row = nt * 16 + rl;
#pragma unroll
                for (int ks = 0; ks < 4; ++ks) {
                    bf16x8 kf = *(const bf16x8*)&Ks[cur][row * 128 + (((ks * 4 + g) ^ (row & 7)) << 3)];
                    sf[0][nt] = mfma16(kf, qf[0][ks], sf[0][nt]);
                    sf[1][nt] = mfma16(kf, qf[1][ks], sf[1][nt]);
                }
            }
            __builtin_amdgcn_s_setprio(0);

            const bool needMask = (kv0 + 63 > wrow0);  // wave-uniform
            float cf2[2];
            bool chg = false;
#pragma unroll
            for (int mi = 0; mi < 2; ++mi) {
                const int qrow = wrow0 + mi * 16 + rl;
                float mx = -1e30f;
                if (needMask) {
#pragma unroll
                    for (int nt = 0; nt < 4; ++nt)
#pragma unroll
                        for (int r = 0; r < 4; ++r) {
                            const int kcol = kv0 + nt * 16 + g * 4 + r;
                            float s = sf[mi][nt][r];
                            s = (kcol > qrow) ? -1e30f : s;
                            sf[mi][nt][r] = s;
                            mx = fmaxf(mx, s);
                        }
                } else {
#pragma unroll
                    for (int nt = 0; nt < 4; ++nt)
#pragma unroll
                        for (int r = 0; r < 4; ++r) mx = fmaxf(mx, sf[mi][nt][r]);
                }
                mx = fmaxf(mx, __shfl_xor(mx, 16));
                mx = fmaxf(mx, __shfl_xor(mx, 32));
                const float mn = fmaxf(m2s[mi], mx);
                cf2[mi] = __builtin_amdgcn_exp2f(m2s[mi] - mn);
                chg |= (mn > m2s[mi]);
                m2s[mi] = mn;
                float rs = 0.f;
#pragma unroll
                for (int nt = 0; nt < 4; ++nt)
#pragma unroll
                    for (int r = 0; r < 4; ++r) {
                        const float p = __builtin_amdgcn_exp2f(sf[mi][nt][r] - mn);
                        sf[mi][nt][r] = p;
                        rs += p;
                    }
                rs += __shfl_xor(rs, 16);
                rs += __shfl_xor(rs, 32);
                lsum[mi] = lsum[mi] * cf2[mi] + rs;
            }

            if (__any((int)chg)) {
#pragma unroll
                for (int mi = 0; mi < 2; ++mi)
#pragma unroll
                    for (int nt = 0; nt < 8; ++nt)
#pragma unroll
                        for (int r = 0; r < 4; ++r) accO[mi][nt][r] *= cf2[mi];
            }

            // P -> LDS (bf16, swizzled at 16B-chunk granularity), 8B packed writes
            unsigned short* myP = Ps[wid];
#pragma unroll
            for (int mi = 0; mi < 2; ++mi) {
                const int row = mi * 16 + rl;
                const int rx = row & 7;
#pragma unroll
                for (int nt = 0; nt < 4; ++nt) {
                    ushort4_t v;
#pragma unroll
                    for (int r = 0; r < 4; ++r) v[r] = f2bf(sf[mi][nt][r]);
                    const int chunk = nt * 2 + (g >> 1);
                    *(ushort4_t*)&myP[row * 64 + ((chunk ^ rx) << 3) + ((g & 1) << 2)] = v;
                }
            }
        }
        __syncthreads();  // drains V + K-next staging

        if (active) {
            unsigned short* myP = Ps[wid];
            __builtin_amdgcn_s_setprio(1);
#pragma unroll
            for (int ks = 0; ks < 2; ++ks) {
                bf16x8 pa[2];
#pragma unroll
                for (int mi = 0; mi < 2; ++mi) {
                    const int row = mi * 16 + rl;
                    pa[mi] = *(const bf16x8*)&myP[row * 64 + (((ks * 4 + g) ^ (row & 7)) << 3)];
                }
#pragma unroll
                for (int nt = 0; nt < 8; ++nt) {
                    const int vrow = nt * 16 + rl;
                    bf16x8 vf = *(const bf16x8*)&Vs[vrow * 64 + (((ks * 4 + g) ^ (vrow & 7)) << 3)];
                    accO[0][nt] = mfma16(vf, pa[0], accO[0][nt]);
                    accO[1][nt] = mfma16(vf, pa[1], accO[1][nt]);
                }
            }
            __builtin_amdgcn_s_setprio(0);
        }
        __syncthreads();  // all PV reads done before next iter's V stage
        cur ^= 1;
    }

    // accO[mi][nt][r] = O[q=wrow0+mi*16+rl][hd = nt*16 + g*4 + r]
#pragma unroll
    for (int mi = 0; mi < 2; ++mi) {
        const float inv = 1.0f / lsum[mi];
        const int qrow = wrow0 + mi * 16 + rl;
#pragma unroll
        for (int nt = 0; nt < 8; ++nt) {
            ushort4_t v;
#pragma unroll
            for (int r = 0; r < 4; ++r) v[r] = f2bf(accO[mi][nt][r] * inv);
            *(ushort4_t*)&O[(size_t)qrow * D + h * HD + nt * 16 + g * 4] = v;
        }
    }
}

// ---------------- launch ----------------------------------------------------
extern "C" void kernel_launch(void* const* d_in, const int* in_sizes, int n_in,
                              void* d_out, int out_size, void* d_ws, size_t ws_size,
                              hipStream_t stream) {
    const float* hs   = (const float*)d_in[0];
    const float* cosT = (const float*)d_in[2];
    const float* sinT = (const float*)d_in[3];
    const float* Wq   = (const float*)d_in[4];
    const float* Wk   = (const float*)d_in[5];
    const float* Wv   = (const float*)d_in[6];
    const float* Wo   = (const float*)d_in[7];

    char* ws = (char*)d_ws;
    const size_t MB = 1ull << 20;
    unsigned short* hsb = (unsigned short*)(ws);             // 16 MB  [S][D]
    unsigned short* wqb = (unsigned short*)(ws + 16 * MB);   // 32 MB  [D][D]
    unsigned short* wkb = (unsigned short*)(ws + 48 * MB);
    unsigned short* wvb = (unsigned short*)(ws + 80 * MB);
    unsigned short* wob = (unsigned short*)(ws + 112 * MB);
    unsigned short* Qb  = (unsigned short*)(ws + 144 * MB);  // 16 MB [S][D]
    unsigned short* Kb  = (unsigned short*)(ws + 160 * MB);  // 16 MB [S][D]
    unsigned short* Vt  = (unsigned short*)(ws + 176 * MB);  // 16 MB [D][S] (V^T)
    unsigned short* AOb = (unsigned short*)(ws + 192 * MB);  // 16 MB [S][D]

    cvt_all<<<4096 + 4 * 8192, 256, 0, stream>>>(hs, Wq, Wk, Wv, Wo,
                                                 hsb, wqb, wkb, wvb, wob);

    gemm_qkv<<<1536, 256, 0, stream>>>(hsb, wqb, wkb, wvb, Qb, Kb, Vt);

    rope_kernel<<<2048, 256, 0, stream>>>(Qb, Kb, cosT, sinT);

    flash_attn<<<dim3(NQT * H), 256, 0, stream>>>(Qb, Kb, Vt, AOb);

    gemm_out<<<512, 256, 0, stream>>>(AOb, wob, (float*)d_out);
}

// Round 6
// 484.393 us; speedup vs baseline: 1.1281x; 1.1281x over previous
//
#include <hip/hip_runtime.h>
#include <hip/hip_bf16.h>
#include <stdint.h>

#define DEV __device__ __forceinline__

typedef __bf16 bf16x8 __attribute__((ext_vector_type(8)));
typedef float f32x4 __attribute__((ext_vector_type(4)));
typedef unsigned short ushort8_t __attribute__((ext_vector_type(8)));
typedef unsigned short ushort4_t __attribute__((ext_vector_type(4)));

constexpr int S = 2048;
constexpr int D = 4096;
constexpr int H = 32;
constexpr int HD = 128;
constexpr float kSc = 0.08838834764831845f * 1.4426950408889634f;  // 1/sqrt(HD) * log2(e)

DEV unsigned short f2bf(float f) {
    uint32_t u = __builtin_bit_cast(uint32_t, f);
    u += 0x7fffu + ((u >> 16) & 1u);
    return (unsigned short)(u >> 16);
}
DEV float bf2f(unsigned short h) {
    uint32_t u = ((uint32_t)h) << 16;
    return __builtin_bit_cast(float, u);
}

DEV void gload_lds16(const void* g, void* l) {
    __builtin_amdgcn_global_load_lds(
        (const __attribute__((address_space(1))) void*)g,
        (__attribute__((address_space(3))) void*)l,
        16, 0, 0);
}

DEV f32x4 mfma16(bf16x8 a, bf16x8 b, f32x4 c) {
    return __builtin_amdgcn_mfma_f32_16x16x32_bf16(a, b, c, 0, 0, 0);
}

// ---------------- fp32 -> bf16 convert, all 5 tensors in one dispatch -------
__global__ __launch_bounds__(256) void cvt_all(const float* __restrict__ hs,
                                               const float* __restrict__ w0,
                                               const float* __restrict__ w1,
                                               const float* __restrict__ w2,
                                               const float* __restrict__ w3,
                                               unsigned short* __restrict__ hsb,
                                               unsigned short* __restrict__ o0,
                                               unsigned short* __restrict__ o1,
                                               unsigned short* __restrict__ o2,
                                               unsigned short* __restrict__ o3) {
    const int b = blockIdx.x;
    const float* in;
    unsigned short* out;
    size_t blk;
    if (b < 4096) {
        in = hs; out = hsb; blk = (size_t)b;
    } else {
        const int i = b - 4096;
        const int w = i >> 13;
        const int r = i & 8191;
        in  = (w == 0) ? w0 : (w == 1) ? w1 : (w == 2) ? w2 : w3;
        out = (w == 0) ? o0 : (w == 1) ? o1 : (w == 2) ? o2 : o3;
        blk = (size_t)r;
    }
    const size_t i8 = blk * 256 + threadIdx.x;
    f32x4 a = ((const f32x4*)in)[2 * i8];
    f32x4 c = ((const f32x4*)in)[2 * i8 + 1];
    ushort8_t o;
    o[0] = f2bf(a[0]); o[1] = f2bf(a[1]); o[2] = f2bf(a[2]); o[3] = f2bf(a[3]);
    o[4] = f2bf(c[0]); o[5] = f2bf(c[1]); o[6] = f2bf(c[2]); o[7] = f2bf(c[3]);
    ((ushort8_t*)out)[i8] = o;
}

// ---------------- fused QKV GEMM, 256x256 tile, 8-phase pipeline ------------
// C[m][n] = sum_k hs[m][k]*W[n][k], W in {Wq,Wk,Wv} per 256-col tile (16 tiles
// each, no straddle). 512 thr = 8 waves (2M x 4N); wave output 128x64.
// LDS: 4 rotating half-tile slots per operand (16KB each, slot(t,h)=(2t+h)&3).
// Per phase: ds_read quadrant (+B at q0) | stage 1 half-tile | vmcnt@ph4/8 |
// barrier | MFMA(16) | barrier.  Stage schedule (iter i, e=2i,o=2i+1):
//   ph1:A0(o) ph2:A1(o) ph3:B0(e+2) ph4:B1(e+2)+vmcnt(4)
//   ph5:A0(e+2) ph6:A1(e+2) ph7:B0(o+2) ph8:B1(o+2)+vmcnt(4)
// Slot-free / landed-guarantee analysis: A(t) read all 4 phases of tile t by
// its waves -> free after ph4/ph8; vmcnt(4) (=2 units) at ph4 covers issues
// <=ph2 (A(o) before ph5 reads), at ph8 covers <=ph6 (A,B(e+2) before next
// iter ph1). st_16x32 swizzle byte^=((byte>>9)&1)<<5 on reads, inverse
// (involution) pre-applied to global stage sources; LDS dests linear.
__global__ __launch_bounds__(512, 2) void gemm_qkv8(const unsigned short* __restrict__ Ap,
                                                    const unsigned short* __restrict__ wq,
                                                    const unsigned short* __restrict__ wk,
                                                    const unsigned short* __restrict__ wv,
                                                    unsigned short* __restrict__ Qb,
                                                    unsigned short* __restrict__ Kb,
                                                    unsigned short* __restrict__ Vt) {
    extern __shared__ unsigned short lds8[];
    unsigned short (*As)[8192] = (unsigned short(*)[8192])lds8;            // 4 x 16KB
    unsigned short (*Bs)[8192] = (unsigned short(*)[8192])(lds8 + 32768);  // 4 x 16KB

    const int tix = threadIdx.x;
    const int lane = tix & 63;
    const int w = tix >> 6;
    const int g = (lane >> 4);
    const int rl = lane & 15;
    const int wm = w >> 2;          // 0..1 : A half
    const int wn = w & 3;           // 0..3
    const int bh = wn >> 1;         // B half
    const int bc0 = (wn & 1) * 64;  // col base within B half

    const int bid = blockIdx.x;     // 384 = 8 xcd * 48; n-fast within XCD (R4 winner)
    const int wg = (bid & 7) * 48 + (bid >> 3);
    const int xx = wg % 48;
    const int yy = wg / 48;
    const int m0 = yy * 256;
    const int n0g = xx * 256;
    const int wsel = n0g >> 12;     // 0:Q 1:K 2:V
    const int n0 = n0g & 4095;
    const unsigned short* Bp = (wsel == 0) ? wq : (wsel == 1) ? wk : wv;

    // stage source pre-swizzle: dest byte d=(u*512+tix)*16 ; src=swz(d)
    int srow[2], scol[2];
#pragma unroll
    for (int u = 0; u < 2; ++u) {
        const int d = (u * 512 + tix) * 16;
        const int sby = d ^ (((d >> 9) & 1) << 5);
        srow[u] = sby >> 7;
        scol[u] = (sby & 127) >> 1;
    }

    const char* aBase[2] = {(const char*)As[wm], (const char*)As[2 + wm]};
    const char* bBase[2] = {(const char*)Bs[bh], (const char*)Bs[2 + bh]};

    f32x4 acc[4][2][4] = {};
    bf16x8 bfr[4][2];

#define STG_A(kt, h, slot)                                                        \
    if ((kt) < 64) {                                                              \
        _Pragma("unroll") for (int u = 0; u < 2; ++u)                             \
            gload_lds16(Ap + (size_t)(m0 + (h) * 128 + srow[u]) * 4096 +          \
                            (kt) * 64 + scol[u],                                  \
                        &As[slot][(u * 512 + tix) * 8]);                          \
    }
#define STG_B(kt, h, slot)                                                        \
    if ((kt) < 64) {                                                              \
        _Pragma("unroll") for (int u = 0; u < 2; ++u)                             \
            gload_lds16(Bp + (size_t)(n0 + (h) * 128 + srow[u]) * 4096 +          \
                            (kt) * 64 + scol[u],                                  \
                        &Bs[slot][(u * 512 + tix) * 8]);                          \
    }

#define PHASE(pt, q, STG, VM)                                                     \
    {                                                                             \
        bf16x8 af[2][2];                                                          \
        _Pragma("unroll") for (int mi = 0; mi < 2; ++mi)                          \
        _Pragma("unroll") for (int ks = 0; ks < 2; ++ks) {                        \
            int ab = ((q) * 32 + mi * 16 + rl) * 128 + ks * 64 + g * 16;          \
            ab ^= ((ab >> 9) & 1) << 5;                                           \
            af[mi][ks] = *(const bf16x8*)(aBase[pt] + ab);                        \
        }                                                                         \
        if ((q) == 0) {                                                           \
            _Pragma("unroll") for (int nt = 0; nt < 4; ++nt)                      \
            _Pragma("unroll") for (int ks = 0; ks < 2; ++ks) {                    \
                int bb = (bc0 + nt * 16 + rl) * 128 + ks * 64 + g * 16;           \
                bb ^= ((bb >> 9) & 1) << 5;                                       \
                bfr[nt][ks] = *(const bf16x8*)(bBase[pt] + bb);                   \
            }                                                                     \
        }                                                                         \
        STG;                                                                      \
        if (VM) asm volatile("s_waitcnt vmcnt(4)" ::: "memory");                  \
        __builtin_amdgcn_s_barrier();                                             \
        __builtin_amdgcn_s_setprio(1);                                            \
        _Pragma("unroll") for (int ks = 0; ks < 2; ++ks)                          \
        _Pragma("unroll") for (int mi = 0; mi < 2; ++mi)                          \
        _Pragma("unroll") for (int nt = 0; nt < 4; ++nt)                          \
            acc[q][mi][nt] = mfma16(af[mi][ks], bfr[nt][ks], acc[q][mi][nt]);     \
        __builtin_amdgcn_s_setprio(0);                                            \
        __builtin_amdgcn_s_barrier();                                             \
    }

    // prologue: tile0 A+B (slots 0,1), tile1 B (slots 2,3); full drain.
    STG_A(0, 0, 0); STG_A(0, 1, 1);
    STG_B(0, 0, 0); STG_B(0, 1, 1);
    STG_B(1, 0, 2); STG_B(1, 1, 3);
    __syncthreads();

    for (int i = 0; i < 32; ++i) {
        const int o = 2 * i + 1, ne = 2 * i + 2, no = 2 * i + 3;
        PHASE(0, 0, STG_A(o, 0, 2), 0)
        PHASE(0, 1, STG_A(o, 1, 3), 0)
        PHASE(0, 2, STG_B(ne, 0, 0), 0)
        PHASE(0, 3, STG_B(ne, 1, 1), 1)
        PHASE(1, 0, STG_A(ne, 0, 0), 0)
        PHASE(1, 1, STG_A(ne, 1, 1), 0)
        PHASE(1, 2, STG_B(no, 0, 2), 0)
        PHASE(1, 3, STG_B(no, 1, 3), 1)
    }
#undef PHASE
#undef STG_A
#undef STG_B

#pragma unroll
    for (int q = 0; q < 4; ++q)
#pragma unroll
        for (int mi = 0; mi < 2; ++mi)
#pragma unroll
            for (int nt = 0; nt < 4; ++nt) {
                const int row0 = m0 + wm * 128 + q * 32 + mi * 16 + g * 4;
                const int colg = n0 + wn * 64 + nt * 16 + rl;
                if (wsel == 2) {
                    ushort4_t v;
#pragma unroll
                    for (int r = 0; r < 4; ++r) v[r] = f2bf(acc[q][mi][nt][r]);
                    *(ushort4_t*)&Vt[(size_t)colg * S + row0] = v;
                } else {
                    unsigned short* o = (wsel == 0) ? Qb : Kb;
#pragma unroll
                    for (int r = 0; r < 4; ++r)
                        o[(size_t)(row0 + r) * 4096 + colg] = f2bf(acc[q][mi][nt][r]);
                }
            }
}

// ---------------- O-projection GEMM: fp32 C = A * Wo^T (R4 mapping) ---------
__global__ __launch_bounds__(256) void gemm_out(const unsigned short* __restrict__ A,
                                                const unsigned short* __restrict__ B,
                                                float* __restrict__ C) {
    __shared__ unsigned short As[128 * 64];
    __shared__ unsigned short Bs[128 * 64];
    const int t = threadIdx.x;
    const int lane = t & 63;
    const int wid = t >> 6;
    const int g = lane >> 4;
    const int rl = lane & 15;

    const int bid = blockIdx.x;  // 512 = 8 * 64
    const int wg = (bid & 7) * 64 + (bid >> 3);
    const int xx = wg % 32;
    const int yy = wg / 32;
    const int m0 = yy * 128;
    const int n0 = xx * 128;

    const int wm = (wid >> 1) * 64;
    const int wn = (wid & 1) * 64;
    constexpr int K = D, N = D;

    f32x4 acc[4][4] = {};

    for (int kt = 0; kt < K; kt += 64) {
#pragma unroll
        for (int r = 0; r < 4; ++r) {
            const int c = r * 256 + t;
            const int row = c >> 3;
            const int src = (c & 7) ^ (row & 7);
            const int dstChunk = r * 256 + wid * 64;
            gload_lds16(A + (size_t)(m0 + row) * K + kt + src * 8, &As[dstChunk * 8]);
            gload_lds16(B + (size_t)(n0 + row) * K + kt + src * 8, &Bs[dstChunk * 8]);
        }
        __syncthreads();
#pragma unroll
        for (int ks = 0; ks < 2; ++ks) {
            bf16x8 af[4], bfv[4];
#pragma unroll
            for (int i = 0; i < 4; ++i) {
                const int rowa = wm + i * 16 + rl;
                af[i] = *(const bf16x8*)&As[rowa * 64 + (((ks * 4 + g) ^ (rowa & 7)) << 3)];
                const int rowb = wn + i * 16 + rl;
                bfv[i] = *(const bf16x8*)&Bs[rowb * 64 + (((ks * 4 + g) ^ (rowb & 7)) << 3)];
            }
#pragma unroll
            for (int mi = 0; mi < 4; ++mi)
#pragma unroll
                for (int ni = 0; ni < 4; ++ni)
                    acc[mi][ni] = mfma16(af[mi], bfv[ni], acc[mi][ni]);
        }
        __syncthreads();
    }

#pragma unroll
    for (int mi = 0; mi < 4; ++mi) {
#pragma unroll
        for (int ni = 0; ni < 4; ++ni) {
            const int grow = m0 + wm + mi * 16 + g * 4;
            const int gcol = n0 + wn + ni * 16 + rl;
#pragma unroll
            for (int r = 0; r < 4; ++r)
                C[(size_t)(grow + r) * N + gcol] = acc[mi][ni][r];
        }
    }
}

// ---------------- RoPE in place on Q and K ([S][D] bf16) --------------------
__global__ __launch_bounds__(256) void rope_kernel(unsigned short* __restrict__ Qb,
                                                   unsigned short* __restrict__ Kb,
                                                   const float* __restrict__ cosT,
                                                   const float* __restrict__ sinT) {
    const int i = blockIdx.x * 256 + threadIdx.x;  // S*H*8 threads
    const int j8 = i & 7;
    const int h = (i >> 3) & 31;
    const int s = i >> 8;
    const size_t base = (size_t)s * D + h * HD + j8 * 8;
    const float* cp = cosT + s * HD + j8 * 8;
    const float* sp = sinT + s * HD + j8 * 8;
    float c1[8], s1[8], c2[8], s2[8];
#pragma unroll
    for (int k = 0; k < 8; ++k) { c1[k] = cp[k]; s1[k] = sp[k]; c2[k] = cp[k + 64]; s2[k] = sp[k + 64]; }

#pragma unroll
    for (int w = 0; w < 2; ++w) {
        unsigned short* p = (w == 0 ? Qb : Kb) + base;
        const float f = (w == 0) ? kSc : 1.0f;
        ushort8_t x1 = *(ushort8_t*)p;
        ushort8_t x2 = *(ushort8_t*)(p + 64);
        ushort8_t o1, o2;
#pragma unroll
        for (int k = 0; k < 8; ++k) {
            const float a = bf2f(x1[k]);
            const float b = bf2f(x2[k]);
            o1[k] = f2bf((a * c1[k] - b * s1[k]) * f);
            o2[k] = f2bf((b * c2[k] + a * s2[k]) * f);
        }
        *(ushort8_t*)p = o1;
        *(ushort8_t*)(p + 64) = o2;
    }
}

// ---------------- causal flash attention (swapped-operand MFMA) -------------
constexpr int NQT = S / 128;  // 16 q-tiles
__global__ __launch_bounds__(256, 2) void flash_attn(const unsigned short* __restrict__ Q,
                                                     const unsigned short* __restrict__ K,
                                                     const unsigned short* __restrict__ V,
                                                     unsigned short* __restrict__ O) {
    __shared__ unsigned short Ks[2][64 * 128];  // [kv][hd], swizzled, dbuf
    __shared__ unsigned short Vs[128 * 64];     // [hd][kv], swizzled
    __shared__ unsigned short Ps[4][32 * 64];   // per-wave P, swizzled

    const int t = threadIdx.x;
    const int lane = t & 63;
    const int wid = t >> 6;
    const int g = lane >> 4;
    const int rl = lane & 15;
    const int bid = blockIdx.x;
    const int qt = (NQT - 1) - (bid >> 5);  // heavy tiles first
    const int h = bid & 31;                 // head in low bits: head-affine XCD
    const int q0 = qt * 128;
    const int wrow0 = q0 + wid * 32;

    bf16x8 qf[2][4];
#pragma unroll
    for (int mi = 0; mi < 2; ++mi) {
        const unsigned short* qp = Q + (size_t)(wrow0 + mi * 16 + rl) * D + h * HD;
#pragma unroll
        for (int ks = 0; ks < 4; ++ks) qf[mi][ks] = *(const bf16x8*)(qp + ks * 32 + g * 8);
    }

    f32x4 accO[2][8] = {};
    float m2s[2] = {-1e30f, -1e30f};
    float lsum[2] = {0.f, 0.f};

    // prologue: stage K tile 0 into buf 0
#pragma unroll
    for (int r = 0; r < 4; ++r) {
        const int c = r * 256 + t;
        const int rowk = c >> 4;
        const int srck = (c & 15) ^ (rowk & 7);
        gload_lds16(K + (size_t)rowk * D + h * HD + srck * 8,
                    &Ks[0][(r * 256 + wid * 64) * 8]);
    }
    __syncthreads();

    int cur = 0;
    const int ntiles = 2 * qt + 2;
    for (int kv = 0; kv < ntiles; ++kv) {
        const int kv0 = kv * 64;
#pragma unroll
        for (int r = 0; r < 4; ++r) {
            const int c = r * 256 + t;
            const int rowv = c >> 3;
            const int srcv = (c & 7) ^ (rowv & 7);
            gload_lds16(V + (size_t)(h * HD + rowv) * S + kv0 + srcv * 8,
                        &Vs[(r * 256 + wid * 64) * 8]);
        }
        if (kv + 1 < ntiles) {
#pragma unroll
            for (int r = 0; r < 4; ++r) {
                const int c = r * 256 + t;
                const int rowk = c >> 4;
                const int srck = (c & 15) ^ (rowk & 7);
                gload_lds16(K + (size_t)(kv0 + 64 + rowk) * D + h * HD + srck * 8,
                            &Ks[cur ^ 1][(r * 256 + wid * 64) * 8]);
            }
        }

        const bool active = kv0 <= wrow0 + 31;  // wave-uniform
        if (active) {
            f32x4 sf[2][4];
#pragma unroll
            for (int mi = 0; mi < 2; ++mi)
#pragma unroll
                for (int nt = 0; nt < 4; ++nt) sf[mi][nt] = f32x4{0.f, 0.f, 0.f, 0.f};
            __builtin_amdgcn_s_setprio(1);
#pragma unroll
            for (int nt = 0; nt < 4; ++nt) {
                const int row = nt * 16 + rl;
#pragma unroll
                for (int ks = 0; ks < 4; ++ks) {
                    bf16x8 kf = *(const bf16x8*)&Ks[cur][row * 128 + (((ks * 4 + g) ^ (row & 7)) << 3)];
                    sf[0][nt] = mfma16(kf, qf[0][ks], sf[0][nt]);
                    sf[1][nt] = mfma16(kf, qf[1][ks], sf[1][nt]);
                }
            }
            __builtin_amdgcn_s_setprio(0);

            const bool needMask = (kv0 + 63 > wrow0);
            float cf2[2];
            bool chg = false;
#pragma unroll
            for (int mi = 0; mi < 2; ++mi) {
                const int qrow = wrow0 + mi * 16 + rl;
                float mx = -1e30f;
                if (needMask) {
#pragma unroll
                    for (int nt = 0; nt < 4; ++nt)
#pragma unroll
                        for (int r = 0; r < 4; ++r) {
                            const int kcol = kv0 + nt * 16 + g * 4 + r;
                            float s = sf[mi][nt][r];
                            s = (kcol > qrow) ? -1e30f : s;
                            sf[mi][nt][r] = s;
                            mx = fmaxf(mx, s);
                        }
                } else {
#pragma unroll
                    for (int nt = 0; nt < 4; ++nt)
#pragma unroll
                        for (int r = 0; r < 4; ++r) mx = fmaxf(mx, sf[mi][nt][r]);
                }
                mx = fmaxf(mx, __shfl_xor(mx, 16));
                mx = fmaxf(mx, __shfl_xor(mx, 32));
                const float mn = fmaxf(m2s[mi], mx);
                cf2[mi] = __builtin_amdgcn_exp2f(m2s[mi] - mn);
                chg |= (mn > m2s[mi]);
                m2s[mi] = mn;
                float rs = 0.f;
#pragma unroll
                for (int nt = 0; nt < 4; ++nt)
#pragma unroll
                    for (int r = 0; r < 4; ++r) {
                        const float p = __builtin_amdgcn_exp2f(sf[mi][nt][r] - mn);
                        sf[mi][nt][r] = p;
                        rs += p;
                    }
                rs += __shfl_xor(rs, 16);
                rs += __shfl_xor(rs, 32);
                lsum[mi] = lsum[mi] * cf2[mi] + rs;
            }

            if (__any((int)chg)) {
#pragma unroll
                for (int mi = 0; mi < 2; ++mi)
#pragma unroll
                    for (int nt = 0; nt < 8; ++nt)
#pragma unroll
                        for (int r = 0; r < 4; ++r) accO[mi][nt][r] *= cf2[mi];
            }

            unsigned short* myP = Ps[wid];
#pragma unroll
            for (int mi = 0; mi < 2; ++mi) {
                const int row = mi * 16 + rl;
                const int rx = row & 7;
#pragma unroll
                for (int nt = 0; nt < 4; ++nt) {
                    ushort4_t v;
#pragma unroll
                    for (int r = 0; r < 4; ++r) v[r] = f2bf(sf[mi][nt][r]);
                    const int chunk = nt * 2 + (g >> 1);
                    *(ushort4_t*)&myP[row * 64 + ((chunk ^ rx) << 3) + ((g & 1) << 2)] = v;
                }
            }
        }
        __syncthreads();

        if (active) {
            unsigned short* myP = Ps[wid];
            __builtin_amdgcn_s_setprio(1);
#pragma unroll
            for (int ks = 0; ks < 2; ++ks) {
                bf16x8 pa[2];
#pragma unroll
                for (int mi = 0; mi < 2; ++mi) {
                    const int row = mi * 16 + rl;
                    pa[mi] = *(const bf16x8*)&myP[row * 64 + (((ks * 4 + g) ^ (row & 7)) << 3)];
                }
#pragma unroll
                for (int nt = 0; nt < 8; ++nt) {
                    const int vrow = nt * 16 + rl;
                    bf16x8 vf = *(const bf16x8*)&Vs[vrow * 64 + (((ks * 4 + g) ^ (vrow & 7)) << 3)];
                    accO[0][nt] = mfma16(vf, pa[0], accO[0][nt]);
                    accO[1][nt] = mfma16(vf, pa[1], accO[1][nt]);
                }
            }
            __builtin_amdgcn_s_setprio(0);
        }
        __syncthreads();
        cur ^= 1;
    }

#pragma unroll
    for (int mi = 0; mi < 2; ++mi) {
        const float inv = 1.0f / lsum[mi];
        const int qrow = wrow0 + mi * 16 + rl;
#pragma unroll
        for (int nt = 0; nt < 8; ++nt) {
            ushort4_t v;
#pragma unroll
            for (int r = 0; r < 4; ++r) v[r] = f2bf(accO[mi][nt][r] * inv);
            *(ushort4_t*)&O[(size_t)qrow * D + h * HD + nt * 16 + g * 4] = v;
        }
    }
}

// ---------------- launch ----------------------------------------------------
extern "C" void kernel_launch(void* const* d_in, const int* in_sizes, int n_in,
                              void* d_out, int out_size, void* d_ws, size_t ws_size,
                              hipStream_t stream) {
    const float* hs   = (const float*)d_in[0];
    const float* cosT = (const float*)d_in[2];
    const float* sinT = (const float*)d_in[3];
    const float* Wq   = (const float*)d_in[4];
    const float* Wk   = (const float*)d_in[5];
    const float* Wv   = (const float*)d_in[6];
    const float* Wo   = (const float*)d_in[7];

    char* ws = (char*)d_ws;
    const size_t MB = 1ull << 20;
    unsigned short* hsb = (unsigned short*)(ws);             // 16 MB  [S][D]
    unsigned short* wqb = (unsigned short*)(ws + 16 * MB);   // 32 MB  [D][D]
    unsigned short* wkb = (unsigned short*)(ws + 48 * MB);
    unsigned short* wvb = (unsigned short*)(ws + 80 * MB);
    unsigned short* wob = (unsigned short*)(ws + 112 * MB);
    unsigned short* Qb  = (unsigned short*)(ws + 144 * MB);  // 16 MB [S][D]
    unsigned short* Kb  = (unsigned short*)(ws + 160 * MB);  // 16 MB [S][D]
    unsigned short* Vt  = (unsigned short*)(ws + 176 * MB);  // 16 MB [D][S] (V^T)
    unsigned short* AOb = (unsigned short*)(ws + 192 * MB);  // 16 MB [S][D]

    cvt_all<<<4096 + 4 * 8192, 256, 0, stream>>>(hs, Wq, Wk, Wv, Wo,
                                                 hsb, wqb, wkb, wvb, wob);

    gemm_qkv8<<<384, 512, 131072, stream>>>(hsb, wqb, wkb, wvb, Qb, Kb, Vt);

    rope_kernel<<<2048, 256, 0, stream>>>(Qb, Kb, cosT, sinT);

    flash_attn<<<dim3(NQT * H), 256, 0, stream>>>(Qb, Kb, Vt, AOb);

    gemm_out<<<512, 256, 0, stream>>>(AOb, wob, (float*)d_out);
}

// Round 7
// 465.625 us; speedup vs baseline: 1.1735x; 1.0403x over previous
//
#include <hip/hip_runtime.h>
#include <hip/hip_bf16.h>
#include <stdint.h>

#define DEV __device__ __forceinline__

typedef __bf16 bf16x8 __attribute__((ext_vector_type(8)));
typedef float f32x4 __attribute__((ext_vector_type(4)));
typedef unsigned short ushort8_t __attribute__((ext_vector_type(8)));
typedef unsigned short ushort4_t __attribute__((ext_vector_type(4)));

constexpr int S = 2048;
constexpr int D = 4096;
constexpr int H = 32;
constexpr int HD = 128;
constexpr float kSc = 0.08838834764831845f * 1.4426950408889634f;  // 1/sqrt(HD) * log2(e)

DEV unsigned short f2bf(float f) {
    uint32_t u = __builtin_bit_cast(uint32_t, f);
    u += 0x7fffu + ((u >> 16) & 1u);
    return (unsigned short)(u >> 16);
}
DEV float bf2f(unsigned short h) {
    uint32_t u = ((uint32_t)h) << 16;
    return __builtin_bit_cast(float, u);
}

DEV void gload_lds16(const void* g, void* l) {
    __builtin_amdgcn_global_load_lds(
        (const __attribute__((address_space(1))) void*)g,
        (__attribute__((address_space(3))) void*)l,
        16, 0, 0);
}

DEV f32x4 mfma16(bf16x8 a, bf16x8 b, f32x4 c) {
    return __builtin_amdgcn_mfma_f32_16x16x32_bf16(a, b, c, 0, 0, 0);
}

// ---------------- fp32 -> bf16 convert, all 5 tensors in one dispatch -------
__global__ __launch_bounds__(256) void cvt_all(const float* __restrict__ hs,
                                               const float* __restrict__ w0,
                                               const float* __restrict__ w1,
                                               const float* __restrict__ w2,
                                               const float* __restrict__ w3,
                                               unsigned short* __restrict__ hsb,
                                               unsigned short* __restrict__ o0,
                                               unsigned short* __restrict__ o1,
                                               unsigned short* __restrict__ o2,
                                               unsigned short* __restrict__ o3) {
    const int b = blockIdx.x;
    const float* in;
    unsigned short* out;
    size_t blk;
    if (b < 4096) {
        in = hs; out = hsb; blk = (size_t)b;
    } else {
        const int i = b - 4096;
        const int w = i >> 13;
        const int r = i & 8191;
        in  = (w == 0) ? w0 : (w == 1) ? w1 : (w == 2) ? w2 : w3;
        out = (w == 0) ? o0 : (w == 1) ? o1 : (w == 2) ? o2 : o3;
        blk = (size_t)r;
    }
    const size_t i8 = blk * 256 + threadIdx.x;
    f32x4 a = ((const f32x4*)in)[2 * i8];
    f32x4 c = ((const f32x4*)in)[2 * i8 + 1];
    ushort8_t o;
    o[0] = f2bf(a[0]); o[1] = f2bf(a[1]); o[2] = f2bf(a[2]); o[3] = f2bf(a[3]);
    o[4] = f2bf(c[0]); o[5] = f2bf(c[1]); o[6] = f2bf(c[2]); o[7] = f2bf(c[3]);
    ((ushort8_t*)out)[i8] = o;
}

// ---------------- fused QKV GEMM, 256x256 tile, 8-phase pipeline ------------
// Same schedule as R6 (which validated); swizzle replaced by the proven
// (row&7) 16B-chunk XOR (G4): LDS[r][chunk j] = global[r][j ^ (r&7)], read at
// chunk ((ks*4+g) ^ (rl&7)) since all fragment rows are = rl (mod 8).
// Column reads now spread 16 rows over 8 chunks -> 2 lanes/slot, row-pair
// stride 2048B = bank-aligned -> 2-way conflict = free (m136).
__global__ __launch_bounds__(512, 2) void gemm_qkv8(const unsigned short* __restrict__ Ap,
                                                    const unsigned short* __restrict__ wq,
                                                    const unsigned short* __restrict__ wk,
                                                    const unsigned short* __restrict__ wv,
                                                    unsigned short* __restrict__ Qb,
                                                    unsigned short* __restrict__ Kb,
                                                    unsigned short* __restrict__ Vt) {
    extern __shared__ unsigned short lds8[];
    unsigned short (*As)[8192] = (unsigned short(*)[8192])lds8;            // 4 x 16KB
    unsigned short (*Bs)[8192] = (unsigned short(*)[8192])(lds8 + 32768);  // 4 x 16KB

    const int tix = threadIdx.x;
    const int lane = tix & 63;
    const int w = tix >> 6;
    const int g = (lane >> 4);
    const int rl = lane & 15;
    const int wm = w >> 2;          // 0..1 : A half
    const int wn = w & 3;           // 0..3
    const int bh = wn >> 1;         // B half
    const int bc0 = (wn & 1) * 64;  // col base within B half
    const int rx = rl & 7;          // per-lane chunk XOR (row&7 == rl&7 here)

    const int bid = blockIdx.x;     // 384 = 8 xcd * 48; n-fast within XCD (R4 winner)
    const int wg = (bid & 7) * 48 + (bid >> 3);
    const int xx = wg % 48;
    const int yy = wg / 48;
    const int m0 = yy * 256;
    const int n0g = xx * 256;
    const int wsel = n0g >> 12;     // 0:Q 1:K 2:V
    const int n0 = n0g & 4095;
    const unsigned short* Bp = (wsel == 0) ? wq : (wsel == 1) ? wk : wv;

    // stage source pre-swizzle: dest 16B-chunk c -> row c>>3, source chunk (c&7)^(row&7)
    int srow[2], scol[2];
#pragma unroll
    for (int u = 0; u < 2; ++u) {
        const int c = u * 512 + tix;               // chunk 0..1023
        srow[u] = c >> 3;                          // row 0..127
        scol[u] = (((c & 7) ^ (srow[u] & 7)) << 3);  // element col in row
    }

    const char* aBase[2] = {(const char*)As[wm], (const char*)As[2 + wm]};
    const char* bBase[2] = {(const char*)Bs[bh], (const char*)Bs[2 + bh]};

    f32x4 acc[4][2][4] = {};
    bf16x8 bfr[4][2];

#define STG_A(kt, h, slot)                                                        \
    if ((kt) < 64) {                                                              \
        _Pragma("unroll") for (int u = 0; u < 2; ++u)                             \
            gload_lds16(Ap + (size_t)(m0 + (h) * 128 + srow[u]) * 4096 +          \
                            (kt) * 64 + scol[u],                                  \
                        &As[slot][(u * 512 + tix) * 8]);                          \
    }
#define STG_B(kt, h, slot)                                                        \
    if ((kt) < 64) {                                                              \
        _Pragma("unroll") for (int u = 0; u < 2; ++u)                             \
            gload_lds16(Bp + (size_t)(n0 + (h) * 128 + srow[u]) * 4096 +          \
                            (kt) * 64 + scol[u],                                  \
                        &Bs[slot][(u * 512 + tix) * 8]);                          \
    }

#define PHASE(pt, q, STG, VM)                                                     \
    {                                                                             \
        bf16x8 af[2][2];                                                          \
        _Pragma("unroll") for (int mi = 0; mi < 2; ++mi)                          \
        _Pragma("unroll") for (int ks = 0; ks < 2; ++ks) {                        \
            const int ab = ((q) * 32 + mi * 16 + rl) * 128 +                      \
                           ((((ks << 2) + g) ^ rx) << 4);                         \
            af[mi][ks] = *(const bf16x8*)(aBase[pt] + ab);                        \
        }                                                                         \
        if ((q) == 0) {                                                           \
            _Pragma("unroll") for (int nt = 0; nt < 4; ++nt)                      \
            _Pragma("unroll") for (int ks = 0; ks < 2; ++ks) {                    \
                const int bb = (bc0 + nt * 16 + rl) * 128 +                       \
                               ((((ks << 2) + g) ^ rx) << 4);                     \
                bfr[nt][ks] = *(const bf16x8*)(bBase[pt] + bb);                   \
            }                                                                     \
        }                                                                         \
        STG;                                                                      \
        if (VM) asm volatile("s_waitcnt vmcnt(4)" ::: "memory");                  \
        __builtin_amdgcn_s_barrier();                                             \
        __builtin_amdgcn_s_setprio(1);                                            \
        _Pragma("unroll") for (int ks = 0; ks < 2; ++ks)                          \
        _Pragma("unroll") for (int mi = 0; mi < 2; ++mi)                          \
        _Pragma("unroll") for (int nt = 0; nt < 4; ++nt)                          \
            acc[q][mi][nt] = mfma16(af[mi][ks], bfr[nt][ks], acc[q][mi][nt]);     \
        __builtin_amdgcn_s_setprio(0);                                            \
        __builtin_amdgcn_s_barrier();                                             \
    }

    // prologue: tile0 A+B (slots 0,1), tile1 B (slots 2,3); full drain.
    STG_A(0, 0, 0); STG_A(0, 1, 1);
    STG_B(0, 0, 0); STG_B(0, 1, 1);
    STG_B(1, 0, 2); STG_B(1, 1, 3);
    __syncthreads();

    for (int i = 0; i < 32; ++i) {
        const int o = 2 * i + 1, ne = 2 * i + 2, no = 2 * i + 3;
        PHASE(0, 0, STG_A(o, 0, 2), 0)
        PHASE(0, 1, STG_A(o, 1, 3), 0)
        PHASE(0, 2, STG_B(ne, 0, 0), 0)
        PHASE(0, 3, STG_B(ne, 1, 1), 1)
        PHASE(1, 0, STG_A(ne, 0, 0), 0)
        PHASE(1, 1, STG_A(ne, 1, 1), 0)
        PHASE(1, 2, STG_B(no, 0, 2), 0)
        PHASE(1, 3, STG_B(no, 1, 3), 1)
    }
#undef PHASE
#undef STG_A
#undef STG_B

#pragma unroll
    for (int q = 0; q < 4; ++q)
#pragma unroll
        for (int mi = 0; mi < 2; ++mi)
#pragma unroll
            for (int nt = 0; nt < 4; ++nt) {
                const int row0 = m0 + wm * 128 + q * 32 + mi * 16 + g * 4;
                const int colg = n0 + wn * 64 + nt * 16 + rl;
                if (wsel == 2) {
                    ushort4_t v;
#pragma unroll
                    for (int r = 0; r < 4; ++r) v[r] = f2bf(acc[q][mi][nt][r]);
                    *(ushort4_t*)&Vt[(size_t)colg * S + row0] = v;
                } else {
                    unsigned short* o = (wsel == 0) ? Qb : Kb;
#pragma unroll
                    for (int r = 0; r < 4; ++r)
                        o[(size_t)(row0 + r) * 4096 + colg] = f2bf(acc[q][mi][nt][r]);
                }
            }
}

// ---------------- O-projection GEMM: fp32 C = A * Wo^T (R4 mapping) ---------
__global__ __launch_bounds__(256) void gemm_out(const unsigned short* __restrict__ A,
                                                const unsigned short* __restrict__ B,
                                                float* __restrict__ C) {
    __shared__ unsigned short As[128 * 64];
    __shared__ unsigned short Bs[128 * 64];
    const int t = threadIdx.x;
    const int lane = t & 63;
    const int wid = t >> 6;
    const int g = lane >> 4;
    const int rl = lane & 15;

    const int bid = blockIdx.x;  // 512 = 8 * 64
    const int wg = (bid & 7) * 64 + (bid >> 3);
    const int xx = wg % 32;
    const int yy = wg / 32;
    const int m0 = yy * 128;
    const int n0 = xx * 128;

    const int wm = (wid >> 1) * 64;
    const int wn = (wid & 1) * 64;
    constexpr int K = D, N = D;

    f32x4 acc[4][4] = {};

    for (int kt = 0; kt < K; kt += 64) {
#pragma unroll
        for (int r = 0; r < 4; ++r) {
            const int c = r * 256 + t;
            const int row = c >> 3;
            const int src = (c & 7) ^ (row & 7);
            const int dstChunk = r * 256 + wid * 64;
            gload_lds16(A + (size_t)(m0 + row) * K + kt + src * 8, &As[dstChunk * 8]);
            gload_lds16(B + (size_t)(n0 + row) * K + kt + src * 8, &Bs[dstChunk * 8]);
        }
        __syncthreads();
#pragma unroll
        for (int ks = 0; ks < 2; ++ks) {
            bf16x8 af[4], bfv[4];
#pragma unroll
            for (int i = 0; i < 4; ++i) {
                const int rowa = wm + i * 16 + rl;
                af[i] = *(const bf16x8*)&As[rowa * 64 + (((ks * 4 + g) ^ (rowa & 7)) << 3)];
                const int rowb = wn + i * 16 + rl;
                bfv[i] = *(const bf16x8*)&Bs[rowb * 64 + (((ks * 4 + g) ^ (rowb & 7)) << 3)];
            }
#pragma unroll
            for (int mi = 0; mi < 4; ++mi)
#pragma unroll
                for (int ni = 0; ni < 4; ++ni)
                    acc[mi][ni] = mfma16(af[mi], bfv[ni], acc[mi][ni]);
        }
        __syncthreads();
    }

#pragma unroll
    for (int mi = 0; mi < 4; ++mi) {
#pragma unroll
        for (int ni = 0; ni < 4; ++ni) {
            const int grow = m0 + wm + mi * 16 + g * 4;
            const int gcol = n0 + wn + ni * 16 + rl;
#pragma unroll
            for (int r = 0; r < 4; ++r)
                C[(size_t)(grow + r) * N + gcol] = acc[mi][ni][r];
        }
    }
}

// ---------------- RoPE in place on Q and K ([S][D] bf16) --------------------
__global__ __launch_bounds__(256) void rope_kernel(unsigned short* __restrict__ Qb,
                                                   unsigned short* __restrict__ Kb,
                                                   const float* __restrict__ cosT,
                                                   const float* __restrict__ sinT) {
    const int i = blockIdx.x * 256 + threadIdx.x;  // S*H*8 threads
    const int j8 = i & 7;
    const int h = (i >> 3) & 31;
    const int s = i >> 8;
    const size_t base = (size_t)s * D + h * HD + j8 * 8;
    const float* cp = cosT + s * HD + j8 * 8;
    const float* sp = sinT + s * HD + j8 * 8;
    float c1[8], s1[8], c2[8], s2[8];
#pragma unroll
    for (int k = 0; k < 8; ++k) { c1[k] = cp[k]; s1[k] = sp[k]; c2[k] = cp[k + 64]; s2[k] = sp[k + 64]; }

#pragma unroll
    for (int w = 0; w < 2; ++w) {
        unsigned short* p = (w == 0 ? Qb : Kb) + base;
        const float f = (w == 0) ? kSc : 1.0f;
        ushort8_t x1 = *(ushort8_t*)p;
        ushort8_t x2 = *(ushort8_t*)(p + 64);
        ushort8_t o1, o2;
#pragma unroll
        for (int k = 0; k < 8; ++k) {
            const float a = bf2f(x1[k]);
            const float b = bf2f(x2[k]);
            o1[k] = f2bf((a * c1[k] - b * s1[k]) * f);
            o2[k] = f2bf((b * c2[k] + a * s2[k]) * f);
        }
        *(ushort8_t*)p = o1;
        *(ushort8_t*)(p + 64) = o2;
    }
}

// ---------------- causal flash attention (swapped-operand MFMA) -------------
constexpr int NQT = S / 128;  // 16 q-tiles
__global__ __launch_bounds__(256, 2) void flash_attn(const unsigned short* __restrict__ Q,
                                                     const unsigned short* __restrict__ K,
                                                     const unsigned short* __restrict__ V,
                                                     unsigned short* __restrict__ O) {
    __shared__ unsigned short Ks[2][64 * 128];  // [kv][hd], swizzled, dbuf
    __shared__ unsigned short Vs[128 * 64];     // [hd][kv], swizzled
    __shared__ unsigned short Ps[4][32 * 64];   // per-wave P, swizzled

    const int t = threadIdx.x;
    const int lane = t & 63;
    const int wid = t >> 6;
    const int g = lane >> 4;
    const int rl = lane & 15;
    const int bid = blockIdx.x;
    const int qt = (NQT - 1) - (bid >> 5);  // heavy tiles first
    const int h = bid & 31;                 // head in low bits: head-affine XCD
    const int q0 = qt * 128;
    const int wrow0 = q0 + wid * 32;

    bf16x8 qf[2][4];
#pragma unroll
    for (int mi = 0; mi < 2; ++mi) {
        const unsigned short* qp = Q + (size_t)(wrow0 + mi * 16 + rl) * D + h * HD;
#pragma unroll
        for (int ks = 0; ks < 4; ++ks) qf[mi][ks] = *(const bf16x8*)(qp + ks * 32 + g * 8);
    }

    f32x4 accO[2][8] = {};
    float m2s[2] = {-1e30f, -1e30f};
    float lsum[2] = {0.f, 0.f};

    // prologue: stage K tile 0 into buf 0
#pragma unroll
    for (int r = 0; r < 4; ++r) {
        const int c = r * 256 + t;
        const int rowk = c >> 4;
        const int srck = (c & 15) ^ (rowk & 7);
        gload_lds16(K + (size_t)rowk * D + h * HD + srck * 8,
                    &Ks[0][(r * 256 + wid * 64) * 8]);
    }
    __syncthreads();

    int cur = 0;
    const int ntiles = 2 * qt + 2;
    for (int kv = 0; kv < ntiles; ++kv) {
        const int kv0 = kv * 64;
#pragma unroll
        for (int r = 0; r < 4; ++r) {
            const int c = r * 256 + t;
            const int rowv = c >> 3;
            const int srcv = (c & 7) ^ (rowv & 7);
            gload_lds16(V + (size_t)(h * HD + rowv) * S + kv0 + srcv * 8,
                        &Vs[(r * 256 + wid * 64) * 8]);
        }
        if (kv + 1 < ntiles) {
#pragma unroll
            for (int r = 0; r < 4; ++r) {
                const int c = r * 256 + t;
                const int rowk = c >> 4;
                const int srck = (c & 15) ^ (rowk & 7);
                gload_lds16(K + (size_t)(kv0 + 64 + rowk) * D + h * HD + srck * 8,
                            &Ks[cur ^ 1][(r * 256 + wid * 64) * 8]);
            }
        }

        const bool active = kv0 <= wrow0 + 31;  // wave-uniform
        if (active) {
            f32x4 sf[2][4];
#pragma unroll
            for (int mi = 0; mi < 2; ++mi)
#pragma unroll
                for (int nt = 0; nt < 4; ++nt) sf[mi][nt] = f32x4{0.f, 0.f, 0.f, 0.f};
            __builtin_amdgcn_s_setprio(1);
#pragma unroll
            for (int nt = 0; nt < 4; ++nt) {
                const int row = nt * 16 + rl;
#pragma unroll
                for (int ks = 0; ks < 4; ++ks) {
                    bf16x8 kf = *(const bf16x8*)&Ks[cur][row * 128 + (((ks * 4 + g) ^ (row & 7)) << 3)];
                    sf[0][nt] = mfma16(kf, qf[0][ks], sf[0][nt]);
                    sf[1][nt] = mfma16(kf, qf[1][ks], sf[1][nt]);
                }
            }
            __builtin_amdgcn_s_setprio(0);

            const bool needMask = (kv0 + 63 > wrow0);
            float cf2[2];
            bool chg = false;
#pragma unroll
            for (int mi = 0; mi < 2; ++mi) {
                const int qrow = wrow0 + mi * 16 + rl;
                float mx = -1e30f;
                if (needMask) {
#pragma unroll
                    for (int nt = 0; nt < 4; ++nt)
#pragma unroll
                        for (int r = 0; r < 4; ++r) {
                            const int kcol = kv0 + nt * 16 + g * 4 + r;
                            float s = sf[mi][nt][r];
                            s = (kcol > qrow) ? -1e30f : s;
                            sf[mi][nt][r] = s;
                            mx = fmaxf(mx, s);
                        }
                } else {
#pragma unroll
                    for (int nt = 0; nt < 4; ++nt)
#pragma unroll
                        for (int r = 0; r < 4; ++r) mx = fmaxf(mx, sf[mi][nt][r]);
                }
                mx = fmaxf(mx, __shfl_xor(mx, 16));
                mx = fmaxf(mx, __shfl_xor(mx, 32));
                const float mn = fmaxf(m2s[mi], mx);
                cf2[mi] = __builtin_amdgcn_exp2f(m2s[mi] - mn);
                chg |= (mn > m2s[mi]);
                m2s[mi] = mn;
                float rs = 0.f;
#pragma unroll
                for (int nt = 0; nt < 4; ++nt)
#pragma unroll
                    for (int r = 0; r < 4; ++r) {
                        const float p = __builtin_amdgcn_exp2f(sf[mi][nt][r] - mn);
                        sf[mi][nt][r] = p;
                        rs += p;
                    }
                rs += __shfl_xor(rs, 16);
                rs += __shfl_xor(rs, 32);
                lsum[mi] = lsum[mi] * cf2[mi] + rs;
            }

            if (__any((int)chg)) {
#pragma unroll
                for (int mi = 0; mi < 2; ++mi)
#pragma unroll
                    for (int nt = 0; nt < 8; ++nt)
#pragma unroll
                        for (int r = 0; r < 4; ++r) accO[mi][nt][r] *= cf2[mi];
            }

            unsigned short* myP = Ps[wid];
#pragma unroll
            for (int mi = 0; mi < 2; ++mi) {
                const int row = mi * 16 + rl;
                const int rxp = row & 7;
#pragma unroll
                for (int nt = 0; nt < 4; ++nt) {
                    ushort4_t v;
#pragma unroll
                    for (int r = 0; r < 4; ++r) v[r] = f2bf(sf[mi][nt][r]);
                    const int chunk = nt * 2 + (g >> 1);
                    *(ushort4_t*)&myP[row * 64 + ((chunk ^ rxp) << 3) + ((g & 1) << 2)] = v;
                }
            }
        }
        __syncthreads();

        if (active) {
            unsigned short* myP = Ps[wid];
            __builtin_amdgcn_s_setprio(1);
#pragma unroll
            for (int ks = 0; ks < 2; ++ks) {
                bf16x8 pa[2];
#pragma unroll
                for (int mi = 0; mi < 2; ++mi) {
                    const int row = mi * 16 + rl;
                    pa[mi] = *(const bf16x8*)&myP[row * 64 + (((ks * 4 + g) ^ (row & 7)) << 3)];
                }
#pragma unroll
                for (int nt = 0; nt < 8; ++nt) {
                    const int vrow = nt * 16 + rl;
                    bf16x8 vf = *(const bf16x8*)&Vs[vrow * 64 + (((ks * 4 + g) ^ (vrow & 7)) << 3)];
                    accO[0][nt] = mfma16(vf, pa[0], accO[0][nt]);
                    accO[1][nt] = mfma16(vf, pa[1], accO[1][nt]);
                }
            }
            __builtin_amdgcn_s_setprio(0);
        }
        __syncthreads();
        cur ^= 1;
    }

#pragma unroll
    for (int mi = 0; mi < 2; ++mi) {
        const float inv = 1.0f / lsum[mi];
        const int qrow = wrow0 + mi * 16 + rl;
#pragma unroll
        for (int nt = 0; nt < 8; ++nt) {
            ushort4_t v;
#pragma unroll
            for (int r = 0; r < 4; ++r) v[r] = f2bf(accO[mi][nt][r] * inv);
            *(ushort4_t*)&O[(size_t)qrow * D + h * HD + nt * 16 + g * 4] = v;
        }
    }
}

// ---------------- launch ----------------------------------------------------
extern "C" void kernel_launch(void* const* d_in, const int* in_sizes, int n_in,
                              void* d_out, int out_size, void* d_ws, size_t ws_size,
                              hipStream_t stream) {
    const float* hs   = (const float*)d_in[0];
    const float* cosT = (const float*)d_in[2];
    const float* sinT = (const float*)d_in[3];
    const float* Wq   = (const float*)d_in[4];
    const float* Wk   = (const float*)d_in[5];
    const float* Wv   = (const float*)d_in[6];
    const float* Wo   = (const float*)d_in[7];

    char* ws = (char*)d_ws;
    const size_t MB = 1ull << 20;
    unsigned short* hsb = (unsigned short*)(ws);             // 16 MB  [S][D]
    unsigned short* wqb = (unsigned short*)(ws + 16 * MB);   // 32 MB  [D][D]
    unsigned short* wkb = (unsigned short*)(ws + 48 * MB);
    unsigned short* wvb = (unsigned short*)(ws + 80 * MB);
    unsigned short* wob = (unsigned short*)(ws + 112 * MB);
    unsigned short* Qb  = (unsigned short*)(ws + 144 * MB);  // 16 MB [S][D]
    unsigned short* Kb  = (unsigned short*)(ws + 160 * MB);  // 16 MB [S][D]
    unsigned short* Vt  = (unsigned short*)(ws + 176 * MB);  // 16 MB [D][S] (V^T)
    unsigned short* AOb = (unsigned short*)(ws + 192 * MB);  // 16 MB [S][D]

    cvt_all<<<4096 + 4 * 8192, 256, 0, stream>>>(hs, Wq, Wk, Wv, Wo,
                                                 hsb, wqb, wkb, wvb, wob);

    gemm_qkv8<<<384, 512, 131072, stream>>>(hsb, wqb, wkb, wvb, Qb, Kb, Vt);

    rope_kernel<<<2048, 256, 0, stream>>>(Qb, Kb, cosT, sinT);

    flash_attn<<<dim3(NQT * H), 256, 0, stream>>>(Qb, Kb, Vt, AOb);

    gemm_out<<<512, 256, 0, stream>>>(AOb, wob, (float*)d_out);
}

// Round 8
// 417.774 us; speedup vs baseline: 1.3079x; 1.1145x over previous
//
#include <hip/hip_runtime.h>
#include <hip/hip_bf16.h>
#include <stdint.h>

#define DEV __device__ __forceinline__

typedef __bf16 bf16x8 __attribute__((ext_vector_type(8)));
typedef float f32x4 __attribute__((ext_vector_type(4)));
typedef unsigned short ushort8_t __attribute__((ext_vector_type(8)));
typedef unsigned short ushort4_t __attribute__((ext_vector_type(4)));

constexpr int S = 2048;
constexpr int D = 4096;
constexpr int H = 32;
constexpr int HD = 128;
constexpr float kSc = 0.08838834764831845f * 1.4426950408889634f;  // 1/sqrt(HD) * log2(e)

DEV unsigned short f2bf(float f) {
    uint32_t u = __builtin_bit_cast(uint32_t, f);
    u += 0x7fffu + ((u >> 16) & 1u);
    return (unsigned short)(u >> 16);
}
DEV float bf2f(unsigned short h) {
    uint32_t u = ((uint32_t)h) << 16;
    return __builtin_bit_cast(float, u);
}

DEV void gload_lds16(const void* g, void* l) {
    __builtin_amdgcn_global_load_lds(
        (const __attribute__((address_space(1))) void*)g,
        (__attribute__((address_space(3))) void*)l,
        16, 0, 0);
}

DEV f32x4 mfma16(bf16x8 a, bf16x8 b, f32x4 c) {
    return __builtin_amdgcn_mfma_f32_16x16x32_bf16(a, b, c, 0, 0, 0);
}

// ---------------- fp32 -> bf16 convert, all 5 tensors in one dispatch -------
__global__ __launch_bounds__(256) void cvt_all(const float* __restrict__ hs,
                                               const float* __restrict__ w0,
                                               const float* __restrict__ w1,
                                               const float* __restrict__ w2,
                                               const float* __restrict__ w3,
                                               unsigned short* __restrict__ hsb,
                                               unsigned short* __restrict__ o0,
                                               unsigned short* __restrict__ o1,
                                               unsigned short* __restrict__ o2,
                                               unsigned short* __restrict__ o3) {
    const int b = blockIdx.x;
    const float* in;
    unsigned short* out;
    size_t blk;
    if (b < 4096) {
        in = hs; out = hsb; blk = (size_t)b;
    } else {
        const int i = b - 4096;
        const int w = i >> 13;
        const int r = i & 8191;
        in  = (w == 0) ? w0 : (w == 1) ? w1 : (w == 2) ? w2 : w3;
        out = (w == 0) ? o0 : (w == 1) ? o1 : (w == 2) ? o2 : o3;
        blk = (size_t)r;
    }
    const size_t i8 = blk * 256 + threadIdx.x;
    f32x4 a = ((const f32x4*)in)[2 * i8];
    f32x4 c = ((const f32x4*)in)[2 * i8 + 1];
    ushort8_t o;
    o[0] = f2bf(a[0]); o[1] = f2bf(a[1]); o[2] = f2bf(a[2]); o[3] = f2bf(a[3]);
    o[4] = f2bf(c[0]); o[5] = f2bf(c[1]); o[6] = f2bf(c[2]); o[7] = f2bf(c[3]);
    ((ushort8_t*)out)[i8] = o;
}

// ---------------- 8-phase 256xBN GEMM template ------------------------------
// C[m][n] = sum_k A[m][k]*B[n][k], A [2048][4096], B [Ntot][4096] row-major.
// 512 thr = 8 waves (2M x 4N); wave owns 128 x BN/4. BK=64, 32 iters x 2 tiles.
// LDS: A 4 rotating half-tile slots (128x64=16KB); B 2 full-tile slots
// (BNx64). Swizzle: (row&7) 16B-chunk XOR both sides (R7-verified, 0 confl).
// Phase schedule per iter i (e=2i o=2i+1):
//  ph1:A0(o)->s2 ph2:A1(o)->s3 ph3:B(e+2)->b0 ph4:vmcnt(NB)
//  ph5:A0(e+2)->s0 ph6:A1(e+2)->s1 ph7:B(o+2)->b1 ph8:vmcnt(NB)
// vmcnt(NB): queue [B_prev NB, A 4, B_cur NB] -> drain-to-NB lands B_prev+A.
// Tail (i=31): ph3/ph7 skip -> invariant broken -> vmcnt(0).
// OMODE 0: QKV split epilogue (B = contiguous [Wq;Wk;Wv]); 1: fp32 C.
template <int BN, int OMODE>
__global__ __launch_bounds__(512, 2) void gemm8(const unsigned short* __restrict__ Ap,
                                                const unsigned short* __restrict__ Bp,
                                                unsigned short* __restrict__ Oq,
                                                unsigned short* __restrict__ Ok,
                                                unsigned short* __restrict__ Ovt,
                                                float* __restrict__ Of) {
    constexpr int NT = BN / 64;  // n-frags per wave (3 or 2)
    constexpr int NB = BN / 64;  // B gloads/thread/tile (3 or 2)
    extern __shared__ unsigned short lds8[];
    unsigned short (*As)[8192] = (unsigned short(*)[8192])lds8;  // 4 x 16KB
    unsigned short* Bs0 = lds8 + 4 * 8192;
    unsigned short* Bs1 = Bs0 + BN * 64;

    const int tix = threadIdx.x;
    const int lane = tix & 63;
    const int w = tix >> 6;
    const int g = lane >> 4;
    const int rl = lane & 15;
    const int wm = w >> 2;
    const int wn = w & 3;
    const int bc0 = wn * (BN / 4);
    const int rx = rl & 7;

    const int yy = blockIdx.x & 7;   // m-tile == XCD (A-panel pinned per XCD)
    const int xx = blockIdx.x >> 3;  // n-tile (B streams, n-fast)
    const int m0 = yy * 256;
    const int n0 = xx * BN;

    int srowA[2], scolA[2];
#pragma unroll
    for (int u = 0; u < 2; ++u) {
        const int c = u * 512 + tix;
        srowA[u] = c >> 3;
        scolA[u] = ((c & 7) ^ (srowA[u] & 7)) << 3;
    }
    int srowB[NB], scolB[NB];
#pragma unroll
    for (int u = 0; u < NB; ++u) {
        const int c = u * 512 + tix;
        srowB[u] = c >> 3;
        scolB[u] = ((c & 7) ^ (srowB[u] & 7)) << 3;
    }

    const char* aBase[2] = {(const char*)As[wm], (const char*)As[2 + wm]};
    const char* bBase[2] = {(const char*)Bs0, (const char*)Bs1};

    f32x4 acc[4][2][NT] = {};
    bf16x8 bfr[NT][2];

#define STG_A8(t, h, slot)                                                        \
    if ((t) < 64) {                                                               \
        _Pragma("unroll") for (int u = 0; u < 2; ++u)                             \
            gload_lds16(Ap + (size_t)(m0 + (h) * 128 + srowA[u]) * 4096 +         \
                            (t) * 64 + scolA[u],                                  \
                        &As[slot][(u * 512 + tix) * 8]);                          \
    }
#define STG_B8(t, slot)                                                           \
    if ((t) < 64) {                                                               \
        unsigned short* bs_ = (slot) ? Bs1 : Bs0;                                 \
        _Pragma("unroll") for (int u = 0; u < NB; ++u)                            \
            gload_lds16(Bp + (size_t)(n0 + srowB[u]) * 4096 +                     \
                            (t) * 64 + scolB[u],                                  \
                        &bs_[(u * 512 + tix) * 8]);                               \
    }

#define PHASE8(pt, q, STG, VM)                                                    \
    {                                                                             \
        bf16x8 af[2][2];                                                          \
        _Pragma("unroll") for (int mi = 0; mi < 2; ++mi)                          \
        _Pragma("unroll") for (int ks = 0; ks < 2; ++ks) {                        \
            const int ab = ((q) * 32 + mi * 16 + rl) * 128 +                      \
                           ((((ks << 2) + g) ^ rx) << 4);                         \
            af[mi][ks] = *(const bf16x8*)(aBase[pt] + ab);                        \
        }                                                                         \
        if ((q) == 0) {                                                           \
            _Pragma("unroll") for (int nt = 0; nt < NT; ++nt)                     \
            _Pragma("unroll") for (int ks = 0; ks < 2; ++ks) {                    \
                const int bb = (bc0 + nt * 16 + rl) * 128 +                       \
                               ((((ks << 2) + g) ^ rx) << 4);                     \
                bfr[nt][ks] = *(const bf16x8*)(bBase[pt] + bb);                   \
            }                                                                     \
        }                                                                         \
        STG;                                                                      \
        if (VM) {                                                                 \
            if (last) {                                                           \
                asm volatile("s_waitcnt vmcnt(0)" ::: "memory");                  \
            } else if constexpr (NB == 3) {                                       \
                asm volatile("s_waitcnt vmcnt(3)" ::: "memory");                  \
            } else {                                                              \
                asm volatile("s_waitcnt vmcnt(2)" ::: "memory");                  \
            }                                                                     \
        }                                                                         \
        __builtin_amdgcn_s_barrier();                                             \
        __builtin_amdgcn_s_setprio(1);                                            \
        _Pragma("unroll") for (int ks = 0; ks < 2; ++ks)                          \
        _Pragma("unroll") for (int mi = 0; mi < 2; ++mi)                          \
        _Pragma("unroll") for (int nt = 0; nt < NT; ++nt)                         \
            acc[q][mi][nt] = mfma16(af[mi][ks], bfr[nt][ks], acc[q][mi][nt]);     \
        __builtin_amdgcn_s_setprio(0);                                            \
        __builtin_amdgcn_s_barrier();                                             \
    }

    // prologue: A(0)->slots 0,1; B(0)->b0; B(1)->b1; full drain.
    STG_A8(0, 0, 0); STG_A8(0, 1, 1);
    STG_B8(0, 0); STG_B8(1, 1);
    __syncthreads();

    for (int i = 0; i < 32; ++i) {
        const bool last = (i == 31);
        const int o = 2 * i + 1, ne = 2 * i + 2, no = 2 * i + 3;
        PHASE8(0, 0, STG_A8(o, 0, 2), 0)
        PHASE8(0, 1, STG_A8(o, 1, 3), 0)
        PHASE8(0, 2, STG_B8(ne, 0), 0)
        PHASE8(0, 3, ((void)0), 1)
        PHASE8(1, 0, STG_A8(ne, 0, 0), 0)
        PHASE8(1, 1, STG_A8(ne, 1, 1), 0)
        PHASE8(1, 2, STG_B8(no, 1), 0)
        PHASE8(1, 3, ((void)0), 1)
    }
#undef PHASE8
#undef STG_A8
#undef STG_B8

#pragma unroll
    for (int q = 0; q < 4; ++q)
#pragma unroll
        for (int mi = 0; mi < 2; ++mi)
#pragma unroll
            for (int nt = 0; nt < NT; ++nt) {
                const int row0 = m0 + wm * 128 + q * 32 + mi * 16 + g * 4;
                const int gc = n0 + bc0 + nt * 16 + rl;
                if constexpr (OMODE == 0) {
                    const int sel = gc >> 12;       // 0:Q 1:K 2:V (16-aligned frag)
                    const int col = gc & 4095;
                    if (sel == 2) {
                        ushort4_t v;
#pragma unroll
                        for (int r = 0; r < 4; ++r) v[r] = f2bf(acc[q][mi][nt][r]);
                        *(ushort4_t*)&Ovt[(size_t)col * S + row0] = v;
                    } else {
                        unsigned short* op = sel ? Ok : Oq;
#pragma unroll
                        for (int r = 0; r < 4; ++r)
                            op[(size_t)(row0 + r) * 4096 + col] = f2bf(acc[q][mi][nt][r]);
                    }
                } else {
#pragma unroll
                    for (int r = 0; r < 4; ++r)
                        Of[(size_t)(row0 + r) * 4096 + gc] = acc[q][mi][nt][r];
                }
            }
}

// ---------------- RoPE in place on Q and K ([S][D] bf16) --------------------
__global__ __launch_bounds__(256) void rope_kernel(unsigned short* __restrict__ Qb,
                                                   unsigned short* __restrict__ Kb,
                                                   const float* __restrict__ cosT,
                                                   const float* __restrict__ sinT) {
    const int i = blockIdx.x * 256 + threadIdx.x;  // S*H*8 threads
    const int j8 = i & 7;
    const int h = (i >> 3) & 31;
    const int s = i >> 8;
    const size_t base = (size_t)s * D + h * HD + j8 * 8;
    const float* cp = cosT + s * HD + j8 * 8;
    const float* sp = sinT + s * HD + j8 * 8;
    float c1[8], s1[8], c2[8], s2[8];
#pragma unroll
    for (int k = 0; k < 8; ++k) { c1[k] = cp[k]; s1[k] = sp[k]; c2[k] = cp[k + 64]; s2[k] = sp[k + 64]; }

#pragma unroll
    for (int w = 0; w < 2; ++w) {
        unsigned short* p = (w == 0 ? Qb : Kb) + base;
        const float f = (w == 0) ? kSc : 1.0f;
        ushort8_t x1 = *(ushort8_t*)p;
        ushort8_t x2 = *(ushort8_t*)(p + 64);
        ushort8_t o1, o2;
#pragma unroll
        for (int k = 0; k < 8; ++k) {
            const float a = bf2f(x1[k]);
            const float b = bf2f(x2[k]);
            o1[k] = f2bf((a * c1[k] - b * s1[k]) * f);
            o2[k] = f2bf((b * c2[k] + a * s2[k]) * f);
        }
        *(ushort8_t*)p = o1;
        *(ushort8_t*)(p + 64) = o2;
    }
}

// ---------------- causal flash attention (swapped-operand MFMA) -------------
constexpr int NQT = S / 128;  // 16 q-tiles
__global__ __launch_bounds__(256, 2) void flash_attn(const unsigned short* __restrict__ Q,
                                                     const unsigned short* __restrict__ K,
                                                     const unsigned short* __restrict__ V,
                                                     unsigned short* __restrict__ O) {
    __shared__ unsigned short Ks[2][64 * 128];  // [kv][hd], swizzled, dbuf
    __shared__ unsigned short Vs[128 * 64];     // [hd][kv], swizzled
    __shared__ unsigned short Ps[4][32 * 64];   // per-wave P, swizzled

    const int t = threadIdx.x;
    const int lane = t & 63;
    const int wid = t >> 6;
    const int g = lane >> 4;
    const int rl = lane & 15;
    const int bid = blockIdx.x;
    const int qt = (NQT - 1) - (bid >> 5);  // heavy tiles first
    const int h = bid & 31;                 // head in low bits: head-affine XCD
    const int q0 = qt * 128;
    const int wrow0 = q0 + wid * 32;

    bf16x8 qf[2][4];
#pragma unroll
    for (int mi = 0; mi < 2; ++mi) {
        const unsigned short* qp = Q + (size_t)(wrow0 + mi * 16 + rl) * D + h * HD;
#pragma unroll
        for (int ks = 0; ks < 4; ++ks) qf[mi][ks] = *(const bf16x8*)(qp + ks * 32 + g * 8);
    }

    f32x4 accO[2][8] = {};
    float m2s[2] = {-1e30f, -1e30f};
    float lsum[2] = {0.f, 0.f};

    // prologue: stage K tile 0 into buf 0
#pragma unroll
    for (int r = 0; r < 4; ++r) {
        const int c = r * 256 + t;
        const int rowk = c >> 4;
        const int srck = (c & 15) ^ (rowk & 7);
        gload_lds16(K + (size_t)rowk * D + h * HD + srck * 8,
                    &Ks[0][(r * 256 + wid * 64) * 8]);
    }
    __syncthreads();

    int cur = 0;
    const int ntiles = 2 * qt + 2;
    for (int kv = 0; kv < ntiles; ++kv) {
        const int kv0 = kv * 64;
#pragma unroll
        for (int r = 0; r < 4; ++r) {
            const int c = r * 256 + t;
            const int rowv = c >> 3;
            const int srcv = (c & 7) ^ (rowv & 7);
            gload_lds16(V + (size_t)(h * HD + rowv) * S + kv0 + srcv * 8,
                        &Vs[(r * 256 + wid * 64) * 8]);
        }
        if (kv + 1 < ntiles) {
#pragma unroll
            for (int r = 0; r < 4; ++r) {
                const int c = r * 256 + t;
                const int rowk = c >> 4;
                const int srck = (c & 15) ^ (rowk & 7);
                gload_lds16(K + (size_t)(kv0 + 64 + rowk) * D + h * HD + srck * 8,
                            &Ks[cur ^ 1][(r * 256 + wid * 64) * 8]);
            }
        }

        const bool active = kv0 <= wrow0 + 31;  // wave-uniform
        if (active) {
            f32x4 sf[2][4];
#pragma unroll
            for (int mi = 0; mi < 2; ++mi)
#pragma unroll
                for (int nt = 0; nt < 4; ++nt) sf[mi][nt] = f32x4{0.f, 0.f, 0.f, 0.f};
            __builtin_amdgcn_s_setprio(1);
#pragma unroll
            for (int nt = 0; nt < 4; ++nt) {
                const int row = nt * 16 + rl;
#pragma unroll
                for (int ks = 0; ks < 4; ++ks) {
                    bf16x8 kf = *(const bf16x8*)&Ks[cur][row * 128 + (((ks * 4 + g) ^ (row & 7)) << 3)];
                    sf[0][nt] = mfma16(kf, qf[0][ks], sf[0][nt]);
                    sf[1][nt] = mfma16(kf, qf[1][ks], sf[1][nt]);
                }
            }
            __builtin_amdgcn_s_setprio(0);

            const bool needMask = (kv0 + 63 > wrow0);
            float cf2[2];
            bool chg = false;
#pragma unroll
            for (int mi = 0; mi < 2; ++mi) {
                const int qrow = wrow0 + mi * 16 + rl;
                float mx = -1e30f;
                if (needMask) {
#pragma unroll
                    for (int nt = 0; nt < 4; ++nt)
#pragma unroll
                        for (int r = 0; r < 4; ++r) {
                            const int kcol = kv0 + nt * 16 + g * 4 + r;
                            float s = sf[mi][nt][r];
                            s = (kcol > qrow) ? -1e30f : s;
                            sf[mi][nt][r] = s;
                            mx = fmaxf(mx, s);
                        }
                } else {
#pragma unroll
                    for (int nt = 0; nt < 4; ++nt)
#pragma unroll
                        for (int r = 0; r < 4; ++r) mx = fmaxf(mx, sf[mi][nt][r]);
                }
                mx = fmaxf(mx, __shfl_xor(mx, 16));
                mx = fmaxf(mx, __shfl_xor(mx, 32));
                const float mn = fmaxf(m2s[mi], mx);
                cf2[mi] = __builtin_amdgcn_exp2f(m2s[mi] - mn);
                chg |= (mn > m2s[mi]);
                m2s[mi] = mn;
                float rs = 0.f;
#pragma unroll
                for (int nt = 0; nt < 4; ++nt)
#pragma unroll
                    for (int r = 0; r < 4; ++r) {
                        const float p = __builtin_amdgcn_exp2f(sf[mi][nt][r] - mn);
                        sf[mi][nt][r] = p;
                        rs += p;
                    }
                rs += __shfl_xor(rs, 16);
                rs += __shfl_xor(rs, 32);
                lsum[mi] = lsum[mi] * cf2[mi] + rs;
            }

            if (__any((int)chg)) {
#pragma unroll
                for (int mi = 0; mi < 2; ++mi)
#pragma unroll
                    for (int nt = 0; nt < 8; ++nt)
#pragma unroll
                        for (int r = 0; r < 4; ++r) accO[mi][nt][r] *= cf2[mi];
            }

            unsigned short* myP = Ps[wid];
#pragma unroll
            for (int mi = 0; mi < 2; ++mi) {
                const int row = mi * 16 + rl;
                const int rxp = row & 7;
#pragma unroll
                for (int nt = 0; nt < 4; ++nt) {
                    ushort4_t v;
#pragma unroll
                    for (int r = 0; r < 4; ++r) v[r] = f2bf(sf[mi][nt][r]);
                    const int chunk = nt * 2 + (g >> 1);
                    *(ushort4_t*)&myP[row * 64 + ((chunk ^ rxp) << 3) + ((g & 1) << 2)] = v;
                }
            }
        }
        __syncthreads();

        if (active) {
            unsigned short* myP = Ps[wid];
            __builtin_amdgcn_s_setprio(1);
#pragma unroll
            for (int ks = 0; ks < 2; ++ks) {
                bf16x8 pa[2];
#pragma unroll
                for (int mi = 0; mi < 2; ++mi) {
                    const int row = mi * 16 + rl;
                    pa[mi] = *(const bf16x8*)&myP[row * 64 + (((ks * 4 + g) ^ (row & 7)) << 3)];
                }
#pragma unroll
                for (int nt = 0; nt < 8; ++nt) {
                    const int vrow = nt * 16 + rl;
                    bf16x8 vf = *(const bf16x8*)&Vs[vrow * 64 + (((ks * 4 + g) ^ (vrow & 7)) << 3)];
                    accO[0][nt] = mfma16(vf, pa[0], accO[0][nt]);
                    accO[1][nt] = mfma16(vf, pa[1], accO[1][nt]);
                }
            }
            __builtin_amdgcn_s_setprio(0);
        }
        __syncthreads();
        cur ^= 1;
    }

#pragma unroll
    for (int mi = 0; mi < 2; ++mi) {
        const float inv = 1.0f / lsum[mi];
        const int qrow = wrow0 + mi * 16 + rl;
#pragma unroll
        for (int nt = 0; nt < 8; ++nt) {
            ushort4_t v;
#pragma unroll
            for (int r = 0; r < 4; ++r) v[r] = f2bf(accO[mi][nt][r] * inv);
            *(ushort4_t*)&O[(size_t)qrow * D + h * HD + nt * 16 + g * 4] = v;
        }
    }
}

// ---------------- launch ----------------------------------------------------
extern "C" void kernel_launch(void* const* d_in, const int* in_sizes, int n_in,
                              void* d_out, int out_size, void* d_ws, size_t ws_size,
                              hipStream_t stream) {
    const float* hs   = (const float*)d_in[0];
    const float* cosT = (const float*)d_in[2];
    const float* sinT = (const float*)d_in[3];
    const float* Wq   = (const float*)d_in[4];
    const float* Wk   = (const float*)d_in[5];
    const float* Wv   = (const float*)d_in[6];
    const float* Wo   = (const float*)d_in[7];

    char* ws = (char*)d_ws;
    const size_t MB = 1ull << 20;
    unsigned short* hsb = (unsigned short*)(ws);             // 16 MB  [S][D]
    unsigned short* wqb = (unsigned short*)(ws + 16 * MB);   // 3x32MB contiguous [12288][4096]
    unsigned short* wkb = (unsigned short*)(ws + 48 * MB);
    unsigned short* wvb = (unsigned short*)(ws + 80 * MB);
    unsigned short* wob = (unsigned short*)(ws + 112 * MB);
    unsigned short* Qb  = (unsigned short*)(ws + 144 * MB);  // 16 MB [S][D]
    unsigned short* Kb  = (unsigned short*)(ws + 160 * MB);  // 16 MB [S][D]
    unsigned short* Vt  = (unsigned short*)(ws + 176 * MB);  // 16 MB [D][S] (V^T)
    unsigned short* AOb = (unsigned short*)(ws + 192 * MB);  // 16 MB [S][D]

    cvt_all<<<4096 + 4 * 8192, 256, 0, stream>>>(hs, Wq, Wk, Wv, Wo,
                                                 hsb, wqb, wkb, wvb, wob);

    // QKV: 256x192 tiles -> 8m x 64n = 512 blocks = exactly 2 rounds/CU.
    gemm8<192, 0><<<512, 512, 114688, stream>>>(hsb, wqb, Qb, Kb, Vt, nullptr);

    rope_kernel<<<2048, 256, 0, stream>>>(Qb, Kb, cosT, sinT);

    flash_attn<<<dim3(NQT * H), 256, 0, stream>>>(Qb, Kb, Vt, AOb);

    // O-proj: 256x128 tiles -> 8m x 32n = 256 blocks = exactly 1 round/CU.
    gemm8<128, 1><<<256, 512, 98304, stream>>>(AOb, wob, nullptr, nullptr, nullptr,
                                               (float*)d_out);
}

// Round 9
// 414.284 us; speedup vs baseline: 1.3190x; 1.0084x over previous
//
#include <hip/hip_runtime.h>
#include <hip/hip_bf16.h>
#include <stdint.h>

#define DEV __device__ __forceinline__

typedef __bf16 bf16x8 __attribute__((ext_vector_type(8)));
typedef float f32x4 __attribute__((ext_vector_type(4)));
typedef unsigned short ushort8_t __attribute__((ext_vector_type(8)));
typedef unsigned short ushort4_t __attribute__((ext_vector_type(4)));

constexpr int S = 2048;
constexpr int D = 4096;
constexpr int H = 32;
constexpr int HD = 128;
constexpr float kSc = 0.08838834764831845f * 1.4426950408889634f;  // 1/sqrt(HD) * log2(e)

DEV unsigned short f2bf(float f) {
    uint32_t u = __builtin_bit_cast(uint32_t, f);
    u += 0x7fffu + ((u >> 16) & 1u);
    return (unsigned short)(u >> 16);
}
DEV float bf2f(unsigned short h) {
    uint32_t u = ((uint32_t)h) << 16;
    return __builtin_bit_cast(float, u);
}

DEV void gload_lds16(const void* g, void* l) {
    __builtin_amdgcn_global_load_lds(
        (const __attribute__((address_space(1))) void*)g,
        (__attribute__((address_space(3))) void*)l,
        16, 0, 0);
}

DEV f32x4 mfma16(bf16x8 a, bf16x8 b, f32x4 c) {
    return __builtin_amdgcn_mfma_f32_16x16x32_bf16(a, b, c, 0, 0, 0);
}

// ---------------- fp32 -> bf16 convert, all 5 tensors in one dispatch -------
__global__ __launch_bounds__(256) void cvt_all(const float* __restrict__ hs,
                                               const float* __restrict__ w0,
                                               const float* __restrict__ w1,
                                               const float* __restrict__ w2,
                                               const float* __restrict__ w3,
                                               unsigned short* __restrict__ hsb,
                                               unsigned short* __restrict__ o0,
                                               unsigned short* __restrict__ o1,
                                               unsigned short* __restrict__ o2,
                                               unsigned short* __restrict__ o3) {
    const int b = blockIdx.x;
    const float* in;
    unsigned short* out;
    size_t blk;
    if (b < 4096) {
        in = hs; out = hsb; blk = (size_t)b;
    } else {
        const int i = b - 4096;
        const int w = i >> 13;
        const int r = i & 8191;
        in  = (w == 0) ? w0 : (w == 1) ? w1 : (w == 2) ? w2 : w3;
        out = (w == 0) ? o0 : (w == 1) ? o1 : (w == 2) ? o2 : o3;
        blk = (size_t)r;
    }
    const size_t i8 = blk * 256 + threadIdx.x;
    f32x4 a = ((const f32x4*)in)[2 * i8];
    f32x4 c = ((const f32x4*)in)[2 * i8 + 1];
    ushort8_t o;
    o[0] = f2bf(a[0]); o[1] = f2bf(a[1]); o[2] = f2bf(a[2]); o[3] = f2bf(a[3]);
    o[4] = f2bf(c[0]); o[5] = f2bf(c[1]); o[6] = f2bf(c[2]); o[7] = f2bf(c[3]);
    ((ushort8_t*)out)[i8] = o;
}

// ---------------- 8-phase 256xBN GEMM template (R8, unchanged) --------------
template <int BN, int OMODE>
__global__ __launch_bounds__(512, 2) void gemm8(const unsigned short* __restrict__ Ap,
                                                const unsigned short* __restrict__ Bp,
                                                unsigned short* __restrict__ Oq,
                                                unsigned short* __restrict__ Ok,
                                                unsigned short* __restrict__ Ovt,
                                                float* __restrict__ Of) {
    constexpr int NT = BN / 64;
    constexpr int NB = BN / 64;
    extern __shared__ unsigned short lds8[];
    unsigned short (*As)[8192] = (unsigned short(*)[8192])lds8;
    unsigned short* Bs0 = lds8 + 4 * 8192;
    unsigned short* Bs1 = Bs0 + BN * 64;

    const int tix = threadIdx.x;
    const int lane = tix & 63;
    const int w = tix >> 6;
    const int g = lane >> 4;
    const int rl = lane & 15;
    const int wm = w >> 2;
    const int wn = w & 3;
    const int bc0 = wn * (BN / 4);
    const int rx = rl & 7;

    const int yy = blockIdx.x & 7;
    const int xx = blockIdx.x >> 3;
    const int m0 = yy * 256;
    const int n0 = xx * BN;

    int srowA[2], scolA[2];
#pragma unroll
    for (int u = 0; u < 2; ++u) {
        const int c = u * 512 + tix;
        srowA[u] = c >> 3;
        scolA[u] = ((c & 7) ^ (srowA[u] & 7)) << 3;
    }
    int srowB[NB], scolB[NB];
#pragma unroll
    for (int u = 0; u < NB; ++u) {
        const int c = u * 512 + tix;
        srowB[u] = c >> 3;
        scolB[u] = ((c & 7) ^ (srowB[u] & 7)) << 3;
    }

    const char* aBase[2] = {(const char*)As[wm], (const char*)As[2 + wm]};
    const char* bBase[2] = {(const char*)Bs0, (const char*)Bs1};

    f32x4 acc[4][2][NT] = {};
    bf16x8 bfr[NT][2];

#define STG_A8(t, h, slot)                                                        \
    if ((t) < 64) {                                                               \
        _Pragma("unroll") for (int u = 0; u < 2; ++u)                             \
            gload_lds16(Ap + (size_t)(m0 + (h) * 128 + srowA[u]) * 4096 +         \
                            (t) * 64 + scolA[u],                                  \
                        &As[slot][(u * 512 + tix) * 8]);                          \
    }
#define STG_B8(t, slot)                                                           \
    if ((t) < 64) {                                                               \
        unsigned short* bs_ = (slot) ? Bs1 : Bs0;                                 \
        _Pragma("unroll") for (int u = 0; u < NB; ++u)                            \
            gload_lds16(Bp + (size_t)(n0 + srowB[u]) * 4096 +                     \
                            (t) * 64 + scolB[u],                                  \
                        &bs_[(u * 512 + tix) * 8]);                               \
    }

#define PHASE8(pt, q, STG, VM)                                                    \
    {                                                                             \
        bf16x8 af[2][2];                                                          \
        _Pragma("unroll") for (int mi = 0; mi < 2; ++mi)                          \
        _Pragma("unroll") for (int ks = 0; ks < 2; ++ks) {                        \
            const int ab = ((q) * 32 + mi * 16 + rl) * 128 +                      \
                           ((((ks << 2) + g) ^ rx) << 4);                         \
            af[mi][ks] = *(const bf16x8*)(aBase[pt] + ab);                        \
        }                                                                         \
        if ((q) == 0) {                                                           \
            _Pragma("unroll") for (int nt = 0; nt < NT; ++nt)                     \
            _Pragma("unroll") for (int ks = 0; ks < 2; ++ks) {                    \
                const int bb = (bc0 + nt * 16 + rl) * 128 +                       \
                               ((((ks << 2) + g) ^ rx) << 4);                     \
                bfr[nt][ks] = *(const bf16x8*)(bBase[pt] + bb);                   \
            }                                                                     \
        }                                                                         \
        STG;                                                                      \
        if (VM) {                                                                 \
            if (last) {                                                           \
                asm volatile("s_waitcnt vmcnt(0)" ::: "memory");                  \
            } else if constexpr (NB == 3) {                                       \
                asm volatile("s_waitcnt vmcnt(3)" ::: "memory");                  \
            } else {                                                              \
                asm volatile("s_waitcnt vmcnt(2)" ::: "memory");                  \
            }                                                                     \
        }                                                                         \
        __builtin_amdgcn_s_barrier();                                             \
        __builtin_amdgcn_s_setprio(1);                                            \
        _Pragma("unroll") for (int ks = 0; ks < 2; ++ks)                          \
        _Pragma("unroll") for (int mi = 0; mi < 2; ++mi)                          \
        _Pragma("unroll") for (int nt = 0; nt < NT; ++nt)                         \
            acc[q][mi][nt] = mfma16(af[mi][ks], bfr[nt][ks], acc[q][mi][nt]);     \
        __builtin_amdgcn_s_setprio(0);                                            \
        __builtin_amdgcn_s_barrier();                                             \
    }

    STG_A8(0, 0, 0); STG_A8(0, 1, 1);
    STG_B8(0, 0); STG_B8(1, 1);
    __syncthreads();

    for (int i = 0; i < 32; ++i) {
        const bool last = (i == 31);
        const int o = 2 * i + 1, ne = 2 * i + 2, no = 2 * i + 3;
        PHASE8(0, 0, STG_A8(o, 0, 2), 0)
        PHASE8(0, 1, STG_A8(o, 1, 3), 0)
        PHASE8(0, 2, STG_B8(ne, 0), 0)
        PHASE8(0, 3, ((void)0), 1)
        PHASE8(1, 0, STG_A8(ne, 0, 0), 0)
        PHASE8(1, 1, STG_A8(ne, 1, 1), 0)
        PHASE8(1, 2, STG_B8(no, 1), 0)
        PHASE8(1, 3, ((void)0), 1)
    }
#undef PHASE8
#undef STG_A8
#undef STG_B8

#pragma unroll
    for (int q = 0; q < 4; ++q)
#pragma unroll
        for (int mi = 0; mi < 2; ++mi)
#pragma unroll
            for (int nt = 0; nt < NT; ++nt) {
                const int row0 = m0 + wm * 128 + q * 32 + mi * 16 + g * 4;
                const int gc = n0 + bc0 + nt * 16 + rl;
                if constexpr (OMODE == 0) {
                    const int sel = gc >> 12;
                    const int col = gc & 4095;
                    if (sel == 2) {
                        ushort4_t v;
#pragma unroll
                        for (int r = 0; r < 4; ++r) v[r] = f2bf(acc[q][mi][nt][r]);
                        *(ushort4_t*)&Ovt[(size_t)col * S + row0] = v;
                    } else {
                        unsigned short* op = sel ? Ok : Oq;
#pragma unroll
                        for (int r = 0; r < 4; ++r)
                            op[(size_t)(row0 + r) * 4096 + col] = f2bf(acc[q][mi][nt][r]);
                    }
                } else {
#pragma unroll
                    for (int r = 0; r < 4; ++r)
                        Of[(size_t)(row0 + r) * 4096 + gc] = acc[q][mi][nt][r];
                }
            }
}

// ---------------- RoPE in place on Q and K ([S][D] bf16) --------------------
__global__ __launch_bounds__(256) void rope_kernel(unsigned short* __restrict__ Qb,
                                                   unsigned short* __restrict__ Kb,
                                                   const float* __restrict__ cosT,
                                                   const float* __restrict__ sinT) {
    const int i = blockIdx.x * 256 + threadIdx.x;  // S*H*8 threads
    const int j8 = i & 7;
    const int h = (i >> 3) & 31;
    const int s = i >> 8;
    const size_t base = (size_t)s * D + h * HD + j8 * 8;
    const float* cp = cosT + s * HD + j8 * 8;
    const float* sp = sinT + s * HD + j8 * 8;
    float c1[8], s1[8], c2[8], s2[8];
#pragma unroll
    for (int k = 0; k < 8; ++k) { c1[k] = cp[k]; s1[k] = sp[k]; c2[k] = cp[k + 64]; s2[k] = sp[k + 64]; }

#pragma unroll
    for (int w = 0; w < 2; ++w) {
        unsigned short* p = (w == 0 ? Qb : Kb) + base;
        const float f = (w == 0) ? kSc : 1.0f;
        ushort8_t x1 = *(ushort8_t*)p;
        ushort8_t x2 = *(ushort8_t*)(p + 64);
        ushort8_t o1, o2;
#pragma unroll
        for (int k = 0; k < 8; ++k) {
            const float a = bf2f(x1[k]);
            const float b = bf2f(x2[k]);
            o1[k] = f2bf((a * c1[k] - b * s1[k]) * f);
            o2[k] = f2bf((b * c2[k] + a * s2[k]) * f);
        }
        *(ushort8_t*)p = o1;
        *(ushort8_t*)(p + 64) = o2;
    }
}

// ---------------- causal flash attention: paired q-tiles --------------------
// 512 thr = 8 waves. Waves 0-3 own 128 q-rows of tile th=8+p (heavy), waves
// 4-7 own tile tl=7-p (light): every block = exactly 36 active-wave-iters ->
// perfect balance, and K/V staging is shared by 2x the q-rows (staging per
// q-row halves vs R8). Grid = 8 pairs x 32 heads = 256 blocks = 1/CU.
// Inner wave algorithm identical to R8 (swapped-operand MFMA, in-reg softmax)
// + defer-max (T13, THR=8 in log2 domain): skip O-rescale while the running
// max grows by <= 8 (P bounded by 2^8; fp32 accum safe).
__global__ __launch_bounds__(512, 2) void flash_attn(const unsigned short* __restrict__ Q,
                                                     const unsigned short* __restrict__ K,
                                                     const unsigned short* __restrict__ V,
                                                     unsigned short* __restrict__ O) {
    extern __shared__ unsigned short ldsA[];
    unsigned short* KsB = ldsA;           // 2 x 8192 elem (2 x 16KB)
    unsigned short* VsB = ldsA + 16384;   // 8192 elem (16KB)
    unsigned short* PsB = ldsA + 24576;   // 8 x 2048 elem (32KB)

    const int t = threadIdx.x;
    const int lane = t & 63;
    const int wid = t >> 6;               // 0..7
    const int g = lane >> 4;
    const int rl = lane & 15;
    const int bid = blockIdx.x;
    const int p = 7 - (bid >> 5);         // heavy pairs first
    const int h = bid & 31;
    const int qt = (wid < 4) ? (8 + p) : (7 - p);
    const int wrow0 = qt * 128 + (wid & 3) * 32;

    bf16x8 qf[2][4];
#pragma unroll
    for (int mi = 0; mi < 2; ++mi) {
        const unsigned short* qp = Q + (size_t)(wrow0 + mi * 16 + rl) * D + h * HD;
#pragma unroll
        for (int ks = 0; ks < 4; ++ks) qf[mi][ks] = *(const bf16x8*)(qp + ks * 32 + g * 8);
    }

    f32x4 accO[2][8] = {};
    float m2s[2] = {-1e30f, -1e30f};
    float lsum[2] = {0.f, 0.f};

    // prologue: stage K tile 0 into buf 0 (512 threads, 2 chunks each)
#pragma unroll
    for (int r = 0; r < 2; ++r) {
        const int c = r * 512 + t;
        const int rowk = c >> 4;
        const int srck = (c & 15) ^ (rowk & 7);
        gload_lds16(K + (size_t)rowk * D + h * HD + srck * 8, &KsB[c * 8]);
    }
    __syncthreads();

    int cur = 0;
    const int ntiles = 2 * (8 + p) + 2;   // driven by the heavy tile
    for (int kv = 0; kv < ntiles; ++kv) {
        const int kv0 = kv * 64;
        // stage V[kv] + prefetch K[kv+1]
#pragma unroll
        for (int r = 0; r < 2; ++r) {
            const int c = r * 512 + t;
            const int rowv = c >> 3;
            const int srcv = (c & 7) ^ (rowv & 7);
            gload_lds16(V + (size_t)(h * HD + rowv) * S + kv0 + srcv * 8, &VsB[c * 8]);
        }
        if (kv + 1 < ntiles) {
#pragma unroll
            for (int r = 0; r < 2; ++r) {
                const int c = r * 512 + t;
                const int rowk = c >> 4;
                const int srck = (c & 15) ^ (rowk & 7);
                gload_lds16(K + (size_t)(kv0 + 64 + rowk) * D + h * HD + srck * 8,
                            &KsB[(cur ^ 1) * 8192 + c * 8]);
            }
        }

        const bool active = kv0 <= wrow0 + 31;  // wave-uniform
        if (active) {
            const unsigned short* KsC = KsB + cur * 8192;
            f32x4 sf[2][4];
#pragma unroll
            for (int mi = 0; mi < 2; ++mi)
#pragma unroll
                for (int nt = 0; nt < 4; ++nt) sf[mi][nt] = f32x4{0.f, 0.f, 0.f, 0.f};
            __builtin_amdgcn_s_setprio(1);
#pragma unroll
            for (int nt = 0; nt < 4; ++nt) {
                const int row = nt * 16 + rl;
#pragma unroll
                for (int ks = 0; ks < 4; ++ks) {
                    bf16x8 kf = *(const bf16x8*)&KsC[row * 128 + (((ks * 4 + g) ^ (row & 7)) << 3)];
                    sf[0][nt] = mfma16(kf, qf[0][ks], sf[0][nt]);
                    sf[1][nt] = mfma16(kf, qf[1][ks], sf[1][nt]);
                }
            }
            __builtin_amdgcn_s_setprio(0);

            const bool needMask = (kv0 + 63 > wrow0);
            float cf2[2];
            bool chg = false;
#pragma unroll
            for (int mi = 0; mi < 2; ++mi) {
                const int qrow = wrow0 + mi * 16 + rl;
                float mx = -1e30f;
                if (needMask) {
#pragma unroll
                    for (int nt = 0; nt < 4; ++nt)
#pragma unroll
                        for (int r = 0; r < 4; ++r) {
                            const int kcol = kv0 + nt * 16 + g * 4 + r;
                            float s = sf[mi][nt][r];
                            s = (kcol > qrow) ? -1e30f : s;
                            sf[mi][nt][r] = s;
                            mx = fmaxf(mx, s);
                        }
                } else {
#pragma unroll
                    for (int nt = 0; nt < 4; ++nt)
#pragma unroll
                        for (int r = 0; r < 4; ++r) mx = fmaxf(mx, sf[mi][nt][r]);
                }
                mx = fmaxf(mx, __shfl_xor(mx, 16));
                mx = fmaxf(mx, __shfl_xor(mx, 32));
                // defer-max: keep old max while growth <= 8 (P <= 2^8, fp32-safe)
                const float mn = (mx <= m2s[mi] + 8.f) ? m2s[mi] : mx;
                cf2[mi] = __builtin_amdgcn_exp2f(m2s[mi] - mn);
                chg |= (mn > m2s[mi]);
                m2s[mi] = mn;
                float rs = 0.f;
#pragma unroll
                for (int nt = 0; nt < 4; ++nt)
#pragma unroll
                    for (int r = 0; r < 4; ++r) {
                        const float pv = __builtin_amdgcn_exp2f(sf[mi][nt][r] - mn);
                        sf[mi][nt][r] = pv;
                        rs += pv;
                    }
                rs += __shfl_xor(rs, 16);
                rs += __shfl_xor(rs, 32);
                lsum[mi] = lsum[mi] * cf2[mi] + rs;
            }

            if (__any((int)chg)) {
#pragma unroll
                for (int mi = 0; mi < 2; ++mi)
#pragma unroll
                    for (int nt = 0; nt < 8; ++nt)
#pragma unroll
                        for (int r = 0; r < 4; ++r) accO[mi][nt][r] *= cf2[mi];
            }

            unsigned short* myP = PsB + wid * 2048;
#pragma unroll
            for (int mi = 0; mi < 2; ++mi) {
                const int row = mi * 16 + rl;
                const int rxp = row & 7;
#pragma unroll
                for (int nt = 0; nt < 4; ++nt) {
                    ushort4_t v;
#pragma unroll
                    for (int r = 0; r < 4; ++r) v[r] = f2bf(sf[mi][nt][r]);
                    const int chunk = nt * 2 + (g >> 1);
                    *(ushort4_t*)&myP[row * 64 + ((chunk ^ rxp) << 3) + ((g & 1) << 2)] = v;
                }
            }
        }
        __syncthreads();  // drains V + K-next staging; P visible

        if (active) {
            unsigned short* myP = PsB + wid * 2048;
            __builtin_amdgcn_s_setprio(1);
#pragma unroll
            for (int ks = 0; ks < 2; ++ks) {
                bf16x8 pa[2];
#pragma unroll
                for (int mi = 0; mi < 2; ++mi) {
                    const int row = mi * 16 + rl;
                    pa[mi] = *(const bf16x8*)&myP[row * 64 + (((ks * 4 + g) ^ (row & 7)) << 3)];
                }
#pragma unroll
                for (int nt = 0; nt < 8; ++nt) {
                    const int vrow = nt * 16 + rl;
                    bf16x8 vf = *(const bf16x8*)&VsB[vrow * 64 + (((ks * 4 + g) ^ (vrow & 7)) << 3)];
                    accO[0][nt] = mfma16(vf, pa[0], accO[0][nt]);
                    accO[1][nt] = mfma16(vf, pa[1], accO[1][nt]);
                }
            }
            __builtin_amdgcn_s_setprio(0);
        }
        __syncthreads();  // all PV reads done before next iter's stages
        cur ^= 1;
    }

#pragma unroll
    for (int mi = 0; mi < 2; ++mi) {
        const float inv = 1.0f / lsum[mi];
        const int qrow = wrow0 + mi * 16 + rl;
#pragma unroll
        for (int nt = 0; nt < 8; ++nt) {
            ushort4_t v;
#pragma unroll
            for (int r = 0; r < 4; ++r) v[r] = f2bf(accO[mi][nt][r] * inv);
            *(ushort4_t*)&O[(size_t)qrow * D + h * HD + nt * 16 + g * 4] = v;
        }
    }
}

// ---------------- launch ----------------------------------------------------
extern "C" void kernel_launch(void* const* d_in, const int* in_sizes, int n_in,
                              void* d_out, int out_size, void* d_ws, size_t ws_size,
                              hipStream_t stream) {
    const float* hs   = (const float*)d_in[0];
    const float* cosT = (const float*)d_in[2];
    const float* sinT = (const float*)d_in[3];
    const float* Wq   = (const float*)d_in[4];
    const float* Wk   = (const float*)d_in[5];
    const float* Wv   = (const float*)d_in[6];
    const float* Wo   = (const float*)d_in[7];

    char* ws = (char*)d_ws;
    const size_t MB = 1ull << 20;
    unsigned short* hsb = (unsigned short*)(ws);             // 16 MB  [S][D]
    unsigned short* wqb = (unsigned short*)(ws + 16 * MB);   // 3x32MB contiguous [12288][4096]
    unsigned short* wkb = (unsigned short*)(ws + 48 * MB);
    unsigned short* wvb = (unsigned short*)(ws + 80 * MB);
    unsigned short* wob = (unsigned short*)(ws + 112 * MB);
    unsigned short* Qb  = (unsigned short*)(ws + 144 * MB);  // 16 MB [S][D]
    unsigned short* Kb  = (unsigned short*)(ws + 160 * MB);  // 16 MB [S][D]
    unsigned short* Vt  = (unsigned short*)(ws + 176 * MB);  // 16 MB [D][S] (V^T)
    unsigned short* AOb = (unsigned short*)(ws + 192 * MB);  // 16 MB [S][D]

    cvt_all<<<4096 + 4 * 8192, 256, 0, stream>>>(hs, Wq, Wk, Wv, Wo,
                                                 hsb, wqb, wkb, wvb, wob);

    // QKV: 256x192 tiles -> 8m x 64n = 512 blocks = exactly 2 rounds/CU.
    gemm8<192, 0><<<512, 512, 114688, stream>>>(hsb, wqb, Qb, Kb, Vt, nullptr);

    rope_kernel<<<2048, 256, 0, stream>>>(Qb, Kb, cosT, sinT);

    // paired q-tiles: 8 pairs x 32 heads = 256 blocks, 512 threads, 80KB LDS.
    flash_attn<<<256, 512, 81920, stream>>>(Qb, Kb, Vt, AOb);

    // O-proj: 256x128 tiles -> 8m x 32n = 256 blocks = exactly 1 round/CU.
    gemm8<128, 1><<<256, 512, 98304, stream>>>(AOb, wob, nullptr, nullptr, nullptr,
                                               (float*)d_out);
}